// Round 11
// baseline (157.869 us; speedup 1.0000x reference)
//
#include <hip/hip_runtime.h>
#include <hip/hip_bf16.h>
#include <math.h>

typedef short s16x8 __attribute__((ext_vector_type(8)));
typedef unsigned u32x2 __attribute__((ext_vector_type(2)));
typedef unsigned u32x4 __attribute__((ext_vector_type(4)));
typedef float f32x4 __attribute__((ext_vector_type(4)));
typedef float f32x16 __attribute__((ext_vector_type(16)));
typedef __hip_bfloat16 bf16;

#define GLD16(g, l)                                                        \
  __builtin_amdgcn_global_load_lds(                                        \
      (const __attribute__((address_space(1))) void*)(g),                  \
      (__attribute__((address_space(3))) void*)(l), 16, 0, 0)

#define MFMA16(a, b, c) __builtin_amdgcn_mfma_f32_16x16x32_bf16((a), (b), (c), 0, 0, 0)
#define MFMA32(a, b, c) __builtin_amdgcn_mfma_f32_32x32x16_bf16((a), (b), (c), 0, 0, 0)

static constexpr int kS = 4096;   // sequence length (64*64)
static constexpr int kD = 768;    // model dim
static constexpr int kNH = 12;    // heads
static constexpr int kHD = 64;    // head dim
static constexpr int kNE = 2304;  // 3*D

// ===================== Kernel 0: fp32 -> bf16 conversion (all 3 tensors) ===
static constexpr int kNX8 = kS * kD / 8;      // 393216
static constexpr int kNWq8 = kNE * kD / 8;    // 221184
static constexpr int kNWp8 = kD * kD / 8;     // 73728

__global__ __launch_bounds__(256)
void k_cvt3(const float* __restrict__ x, const float* __restrict__ wq,
            const float* __restrict__ wp, bf16* __restrict__ xb,
            bf16* __restrict__ wqb, bf16* __restrict__ wpb) {
  int i = blockIdx.x * 256 + threadIdx.x;
  const float* src;
  short* dst;
  if (i < kNX8) {
    src = x; dst = (short*)xb;
  } else if (i < kNX8 + kNWq8) {
    i -= kNX8; src = wq; dst = (short*)wqb;
  } else {
    i -= kNX8 + kNWq8; if (i >= kNWp8) return;
    src = wp; dst = (short*)wpb;
  }
  const f32x4 a = *(const f32x4*)(src + i * 8);
  const f32x4 b = *(const f32x4*)(src + i * 8 + 4);
  s16x8 o;
#pragma unroll
  for (int j = 0; j < 4; ++j) {
    o[j] = (short)__bfloat16_as_ushort(__float2bfloat16(a[j]));
    o[j + 4] = (short)__bfloat16_as_ushort(__float2bfloat16(b[j]));
  }
  *(s16x8*)(dst + i * 8) = o;
}

// ===================== Kernel 1: QKV GEMM (2-phase dbuf) ===================
__global__ __launch_bounds__(256, 2)
void k_qkv(const bf16* __restrict__ X, const bf16* __restrict__ W,
           bf16* __restrict__ Qw, bf16* __restrict__ Kw, bf16* __restrict__ Vw) {
  __shared__ __align__(16) short As[2][128 * 32];
  __shared__ __align__(16) short Bs[2][128 * 32];
  const int tid = threadIdx.x;
  const int wv = tid >> 6, ln = tid & 63;
  const int r = ln & 15, kq = ln >> 4;
  const int bm = blockIdx.x * 128;   // s
  const int bn = blockIdx.y * 128;   // e
  const int wr = wv >> 1, wc = wv & 1;
  const short* Xs = (const short*)X;
  const short* Ws = (const short*)W;

  f32x4 acc[4][4] = {};

  const int c0 = wv * 128 + ln, c1 = c0 + 64;
  const int ra0 = c0 >> 2, ka0 = c0 & 3;
  const int ra1 = c1 >> 2, ka1 = c1 & 3;
  const int off0 = wv * 1024, off1 = off0 + 512;
  const short* gA0 = Xs + (bm + ra0) * kD + ka0 * 8;
  const short* gA1 = Xs + (bm + ra1) * kD + ka1 * 8;
  const short* gB0 = Ws + (bn + ra0) * kD + ka0 * 8;
  const short* gB1 = Ws + (bn + ra1) * kD + ka1 * 8;

  GLD16(gA0, &As[0][off0]);
  GLD16(gA1, &As[0][off1]);
  GLD16(gB0, &Bs[0][off0]);
  GLD16(gB1, &Bs[0][off1]);
  __syncthreads();

  const int NT = kD / 32;  // 24
  for (int t = 0; t < NT; ++t) {
    const short* aCur = As[t & 1];
    const short* bCur = Bs[t & 1];
    if (t + 1 < NT) {
      const int k1 = (t + 1) * 32;
      short* aN = As[(t + 1) & 1];
      short* bN = Bs[(t + 1) & 1];
      GLD16(gA0 + k1, aN + off0);
      GLD16(gA1 + k1, aN + off1);
      GLD16(gB0 + k1, bN + off0);
      GLD16(gB1 + k1, bN + off1);
    }
    s16x8 a[4], b[4];
#pragma unroll
    for (int i = 0; i < 4; ++i)
      a[i] = *(const s16x8*)(aCur + (wr * 64 + i * 16 + r) * 32 + kq * 8);
#pragma unroll
    for (int j = 0; j < 4; ++j)
      b[j] = *(const s16x8*)(bCur + (wc * 64 + j * 16 + r) * 32 + kq * 8);
#pragma unroll
    for (int i = 0; i < 4; ++i)
#pragma unroll
      for (int j = 0; j < 4; ++j) acc[i][j] = MFMA16(a[i], b[j], acc[i][j]);
    __syncthreads();
  }

  const int which = bn / kD;
  bf16* dst = (which == 0) ? Qw : (which == 1) ? Kw : Vw;
  const float scl = (which == 0) ? 0.125f : 1.0f;  // hd^-0.5, exact pow2
  const int ebase = bn - which * kD + wc * 64;
#pragma unroll
  for (int j = 0; j < 4; ++j) {
    const int e = ebase + j * 16 + r;
    const int h = e >> 6, d = e & 63;
#pragma unroll
    for (int i = 0; i < 4; ++i) {
      const int srow = bm + wr * 64 + i * 16 + kq * 4;
#pragma unroll
      for (int rr = 0; rr < 4; ++rr)
        dst[(h * kS + srow + rr) * kHD + d] = __float2bfloat16(acc[i][j][rr] * scl);
    }
  }
}

// ===================== Kernel 2: V transpose ===============================
__global__ __launch_bounds__(256, 2)
void k_vt(const bf16* __restrict__ Vw, bf16* __restrict__ Vt) {
  __shared__ __align__(16) short L[64 * 72];
  const int h = blockIdx.y, st = blockIdx.x;
  const int t = threadIdx.x;
  const short* src = (const short*)Vw + (h * kS + st * 64) * kHD;
  short* dstb = (short*)Vt + h * kHD * kS;
#pragma unroll
  for (int u = 0; u < 2; ++u) {
    const int c = u * 256 + t;
    const int row = c >> 3, ch = c & 7;
    *(s16x8*)(L + row * 72 + ch * 8) = *(const s16x8*)(src + row * kHD + ch * 8);
  }
  __syncthreads();
#pragma unroll
  for (int u = 0; u < 2; ++u) {
    const int c = u * 256 + t;
    const int d = c >> 3, ch = c & 7;
    s16x8 v;
#pragma unroll
    for (int j = 0; j < 8; ++j) v[j] = L[(ch * 8 + j) * 72 + d];
    *(s16x8*)(dstb + d * kS + st * 64 + ch * 8) = v;
  }
}

// ===================== Kernel 3: flash attention, 32x32, kv-split ==========
// Changes vs round 10 (math identical, both cuts remove WORK):
//  (1) K global->VGPR direct (lane-private rows in swapped-QK^T: no cross-
//      lane K sharing exists, so LDS staging of K was pure overhead).
//      KA/KB named register sets, 1-tile-ahead prefetch, static indices.
//  (2) P half-exchange via __builtin_amdgcn_permlane32_swap: one swap fills
//      two A-frag words (swap(own[4k],own[4k+2]) = (apv0, apv2)); replaces
//      8 ds_bpermute + 8 v_cndmask with 4 VALU ops.
//  V stays in LDS (cross-lane layout needed): 2 body-buffers x 2 tiles.
__global__ __launch_bounds__(256, 3)
void k_attn(const bf16* __restrict__ Qw, const bf16* __restrict__ Kw,
            const bf16* __restrict__ Vt, bf16* __restrict__ Att) {
  __shared__ __align__(16) short Vs[2][2][64 * 64];  // [bodybuf][tile][d][kv]
  const int tid = threadIdx.x;
  const int wv = tid >> 6, ln = tid & 63;
  const int qh = wv >> 1;    // q-subtile (32 rows)
  const int kvh = wv & 1;    // kv-half of each 64-tile
  const int col = ln & 31;
  const int lh = ln >> 5;

  // XCD-pair head grouping (bijective): wg -> (pair p, b in [0,192))
  const int wg = blockIdx.x;
  const int p = (wg & 7) >> 1;
  const int b = (((wg >> 3) << 1) | (wg & 1));
  const int hh = 3 * p + (b >> 6);
  const int q0 = (b & 63) * 64;

  const short* Qh = (const short*)Qw + ((size_t)hh * kS + q0 + qh * 32) * kHD;
  const short* Kh = (const short*)Kw + (size_t)hh * kS * kHD;
  const short* Vh = (const short*)Vt + (size_t)hh * kHD * kS;

  // Q as B-operand frags: col = q (ln&31), k = kb*16 + lh*8 + {0..7}
  s16x8 bq[4];
#pragma unroll
  for (int kb = 0; kb < 4; ++kb)
    bq[kb] = *(const s16x8*)(Qh + col * kHD + kb * 16 + lh * 8);

  f32x16 o[2] = {};  // partial O[32q][64d] over this wave's kv-half
  float lp = 0.f;

  // per-lane K row base (lane-private row kvh*32+col; chunks kb*2+lh)
  const short* KhL = Kh + (kvh * 32 + col) * kHD;

  // V staging: 256 threads x 2 chunks per tile; source-side XOR swizzle
  int ldso[2];
  const short* gV[2];
#pragma unroll
  for (int u = 0; u < 2; ++u) {
    const int c = u * 256 + tid;
    const int kr = c >> 3, g = (c & 7) ^ (kr & 7);
    ldso[u] = c * 8;
    gV[u] = Vh + kr * kS + g * 8;
  }

  // ---- prologue: V tiles 0..3 to LDS, K tiles 0,1 to regs ----
#pragma unroll
  for (int u = 0; u < 2; ++u) {
    GLD16(gV[u] + 0 * 64, &Vs[0][0][ldso[u]]);
    GLD16(gV[u] + 1 * 64, &Vs[0][1][ldso[u]]);
  }
  __builtin_amdgcn_sched_barrier(0);  // pin: tiles 0,1 are the oldest vmem ops
#pragma unroll
  for (int u = 0; u < 2; ++u) {
    GLD16(gV[u] + 2 * 64, &Vs[1][0][ldso[u]]);
    GLD16(gV[u] + 3 * 64, &Vs[1][1][ldso[u]]);
  }
  s16x8 KA[4], KB[4];
#pragma unroll
  for (int kb = 0; kb < 4; ++kb) {
    KA[kb] = *(const s16x8*)(KhL + 0 * 64 * kHD + (kb * 2 + lh) * 8);
    KB[kb] = *(const s16x8*)(KhL + 1 * 64 * kHD + (kb * 2 + lh) * 8);
  }
  asm volatile("s_waitcnt vmcnt(12)" ::: "memory");  // V tiles 0,1 landed
  __builtin_amdgcn_s_barrier();

  // per-tile compute pieces (round-9/10 proven math)
  auto qk = [&](const s16x8 (&K4)[4]) -> f32x16 {
    f32x16 z = {};
    __builtin_amdgcn_s_setprio(1);
#pragma unroll
    for (int kb = 0; kb < 4; ++kb) z = MFMA32(K4[kb], bq[kb], z);
    __builtin_amdgcn_s_setprio(0);
    return z;
  };
  auto smpv = [&](const f32x16& z, const short* vsCur) {
    float pv[16];
#pragma unroll
    for (int g = 0; g < 16; ++g) {
      pv[g] = __expf(z[g]);
      lp += pv[g];
    }
    unsigned own[8];
#pragma unroll
    for (int m = 0; m < 4; ++m) {
      own[2 * m] = (unsigned)__bfloat16_as_ushort(__float2bfloat16(pv[4 * m])) |
                   ((unsigned)__bfloat16_as_ushort(__float2bfloat16(pv[4 * m + 1])) << 16);
      own[2 * m + 1] = (unsigned)__bfloat16_as_ushort(__float2bfloat16(pv[4 * m + 2])) |
                       ((unsigned)__bfloat16_as_ushort(__float2bfloat16(pv[4 * m + 3])) << 16);
    }
    __builtin_amdgcn_s_setprio(1);
#pragma unroll
    for (int kvk = 0; kvk < 2; ++kvk) {
      // swap(a,b): a' = [a.lo32, b.lo32], b' = [a.hi32, b.hi32]
      u32x2 sA = __builtin_amdgcn_permlane32_swap(own[4 * kvk + 0], own[4 * kvk + 2], false, false);
      u32x2 sB = __builtin_amdgcn_permlane32_swap(own[4 * kvk + 1], own[4 * kvk + 3], false, false);
      u32x4 apv;
      apv[0] = sA[0];  // lh=0: own[4k]   | lh=1: oth[4k+2]
      apv[1] = sB[0];  // lh=0: own[4k+1] | lh=1: oth[4k+3]
      apv[2] = sA[1];  // lh=0: oth[4k]   | lh=1: own[4k+2]
      apv[3] = sB[1];  // lh=0: oth[4k+1] | lh=1: own[4k+3]
      const s16x8 ap = __builtin_bit_cast(s16x8, apv);
      const int kvg = kvh * 2 + kvk;
#pragma unroll
      for (int db = 0; db < 2; ++db) {
        const int vrow = db * 32 + col;
        const int ch = ((kvg << 1) + lh) ^ (vrow & 7);
        s16x8 vb = *(const s16x8*)(vsCur + vrow * 64 + ch * 8);
        o[db] = MFMA32(ap, vb, o[db]);
      }
    }
    __builtin_amdgcn_s_setprio(0);
  };

  const int NT = kS / 64;  // 64
  for (int bi = 0; bi < NT / 2; ++bi) {
    const int kt = 2 * bi;
    const short* vs0 = Vs[bi & 1][0];
    const short* vs1 = Vs[bi & 1][1];

    f32x16 z0 = qk(KA);
    if (kt + 2 < NT) {  // prefetch K(kt+2) into KA (compiler-tracked waits)
#pragma unroll
      for (int kb = 0; kb < 4; ++kb)
        KA[kb] = *(const s16x8*)(KhL + (kt + 2) * 64 * kHD + (kb * 2 + lh) * 8);
    }
    f32x16 z1 = qk(KB);
    if (kt + 3 < NT) {  // prefetch K(kt+3) into KB
#pragma unroll
      for (int kb = 0; kb < 4; ++kb)
        KB[kb] = *(const s16x8*)(KhL + (kt + 3) * 64 * kHD + (kb * 2 + lh) * 8);
    }
    smpv(z0, vs0);
    smpv(z1, vs1);

    __builtin_amdgcn_s_barrier();  // all waves done reading this body buffer
    if (kt + 4 < NT) {  // refill just-read buffer with tiles kt+4, kt+5
#pragma unroll
      for (int u = 0; u < 2; ++u) {
        GLD16(gV[u] + (kt + 4) * 64, &Vs[bi & 1][0][ldso[u]]);
        GLD16(gV[u] + (kt + 5) * 64, &Vs[bi & 1][1][ldso[u]]);
      }
      // keep only the 4 newest (this body's V) in flight; everything older
      // (prev V pair + K prefetches) is drained -> next body's data is ready
      asm volatile("s_waitcnt vmcnt(4)" ::: "memory");
    } else {
      asm volatile("s_waitcnt vmcnt(0)" ::: "memory");
    }
    __builtin_amdgcn_s_barrier();
  }

  // --- combine kv-halves through (now-dead) V LDS, then store ---
  lp += __shfl_xor(lp, 32);           // add other lh's kv rows within wave
  float* Of = (float*)&Vs[0][0][0];   // [64 q][64 d] fp32 = 16 KB
  float* Lf = (float*)&Vs[1][0][0];   // [64 q] row sums

  if (kvh == 1) {
#pragma unroll
    for (int db = 0; db < 2; ++db)
#pragma unroll
      for (int g = 0; g < 16; ++g) {
        const int qoff = (g & 3) + 8 * (g >> 2) + 4 * lh;
        Of[(qh * 32 + qoff) * 64 + db * 32 + col] = o[db][g];
      }
    if (lh == 0) Lf[qh * 32 + col] = lp;
  }
  __syncthreads();
  if (kvh == 0) {
    lp += Lf[qh * 32 + col];
    const float inv = 1.0f / lp;
    float invq[16];
#pragma unroll
    for (int g = 0; g < 16; ++g) {
      const int qoff = (g & 3) + 8 * (g >> 2) + 4 * lh;
      invq[g] = __shfl(inv, qoff);
    }
#pragma unroll
    for (int db = 0; db < 2; ++db)
#pragma unroll
      for (int g = 0; g < 16; ++g) {
        const int qoff = (g & 3) + 8 * (g >> 2) + 4 * lh;
        const int srow = q0 + qh * 32 + qoff;
        const float val =
            (o[db][g] + Of[(qh * 32 + qoff) * 64 + db * 32 + col]) * invq[g];
        Att[srow * kD + hh * kHD + db * 32 + col] = __float2bfloat16(val);
      }
  }
}

// ===================== Kernel 4: output projection (64x64 tiles, dbuf) =====
__global__ __launch_bounds__(256, 3)
void k_proj(const bf16* __restrict__ A, const bf16* __restrict__ W,
            const float* __restrict__ Bias, float* __restrict__ Out) {
  __shared__ __align__(16) short As[2][64 * 32];
  __shared__ __align__(16) short Bs[2][64 * 32];
  const int tid = threadIdx.x;
  const int wv = tid >> 6, ln = tid & 63;
  const int r = ln & 15, kq = ln >> 4;
  const int bm = blockIdx.x * 64;
  const int bn = blockIdx.y * 64;
  const int wr = wv >> 1, wc = wv & 1;
  const short* Asrc = (const short*)A;
  const short* Wsrc = (const short*)W;

  f32x4 acc[2][2] = {};
  const int c = wv * 64 + ln;
  const int ra = c >> 2, ka = c & 3;
  const int off = wv * 512;
  const short* gA = Asrc + (bm + ra) * kD + ka * 8;
  const short* gB = Wsrc + (bn + ra) * kD + ka * 8;

  GLD16(gA, &As[0][off]);
  GLD16(gB, &Bs[0][off]);
  __syncthreads();

  const int NT = kD / 32;  // 24
  for (int t = 0; t < NT; ++t) {
    const short* aCur = As[t & 1];
    const short* bCur = Bs[t & 1];
    if (t + 1 < NT) {
      const int k1 = (t + 1) * 32;
      GLD16(gA + k1, &As[(t + 1) & 1][off]);
      GLD16(gB + k1, &Bs[(t + 1) & 1][off]);
    }
    s16x8 a[2], b[2];
#pragma unroll
    for (int i = 0; i < 2; ++i)
      a[i] = *(const s16x8*)(aCur + (wr * 32 + i * 16 + r) * 32 + kq * 8);
#pragma unroll
    for (int j = 0; j < 2; ++j)
      b[j] = *(const s16x8*)(bCur + (wc * 32 + j * 16 + r) * 32 + kq * 8);
#pragma unroll
    for (int i = 0; i < 2; ++i)
#pragma unroll
      for (int j = 0; j < 2; ++j) acc[i][j] = MFMA16(a[i], b[j], acc[i][j]);
    __syncthreads();
  }
#pragma unroll
  for (int j = 0; j < 2; ++j) {
    const int e = bn + wc * 32 + j * 16 + r;
    const float bv = Bias[e];
#pragma unroll
    for (int i = 0; i < 2; ++i) {
      const int srow = bm + wr * 32 + i * 16 + kq * 4;
#pragma unroll
      for (int rr = 0; rr < 4; ++rr)
        Out[(srow + rr) * kD + e] = acc[i][j][rr] + bv;
    }
  }
}

// ===================== launcher ============================================
extern "C" void kernel_launch(void* const* d_in, const int* in_sizes, int n_in,
                              void* d_out, int out_size, void* d_ws, size_t ws_size,
                              hipStream_t stream) {
  const float* x = (const float*)d_in[0];
  const float* w_qkv = (const float*)d_in[1];
  const float* w_proj = (const float*)d_in[2];
  const float* b_proj = (const float*)d_in[3];
  float* out = (float*)d_out;

  const size_t HS = (size_t)kNH * kS * kHD;
  const int nX = kS * kD;
  const int nWq = kNE * kD;
  const int nWp = kD * kD;

  bf16* Xb = (bf16*)d_ws;            // x as bf16          [s][d]
  bf16* Wqb = Xb + nX;               // w_qkv as bf16      [e][d]
  bf16* Wpb = Wqb + nWq;             // w_proj as bf16     [e][d]
  bf16* Qw = Wpb + nWp;              // q (pre-scaled)     [h][s][d]
  bf16* Kw = Qw + HS;                // k                  [h][s][d]
  bf16* Vw = Kw + HS;                // v                  [h][s][d]
  bf16* Vt = Vw + HS;                // v transposed       [h][d][s]
  bf16* At = Vt + HS;                // attention output   [s][h*64+d]

  const int totalC = kNX8 + kNWq8 + kNWp8;
  k_cvt3<<<(totalC + 255) / 256, 256, 0, stream>>>(x, w_qkv, w_proj, Xb, Wqb, Wpb);

  k_qkv<<<dim3(kS / 128, kNE / 128), 256, 0, stream>>>(Xb, Wqb, Qw, Kw, Vw);
  k_vt<<<dim3(kS / 64, kNH), 256, 0, stream>>>(Vw, Vt);
  k_attn<<<dim3((kS / 64) * kNH), 256, 0, stream>>>(Qw, Kw, Vt, At);
  k_proj<<<dim3(kS / 64, kD / 64), 256, 0, stream>>>(At, Wpb, b_proj, out);
}

// Round 12
// 133.038 us; speedup vs baseline: 1.1866x; 1.1866x over previous
//
#include <hip/hip_runtime.h>
#include <hip/hip_bf16.h>
#include <math.h>

typedef short s16x8 __attribute__((ext_vector_type(8)));
typedef unsigned u32x2 __attribute__((ext_vector_type(2)));
typedef unsigned u32x4 __attribute__((ext_vector_type(4)));
typedef float f32x4 __attribute__((ext_vector_type(4)));
typedef float f32x16 __attribute__((ext_vector_type(16)));
typedef __hip_bfloat16 bf16;

#define GLD16(g, l)                                                        \
  __builtin_amdgcn_global_load_lds(                                        \
      (const __attribute__((address_space(1))) void*)(g),                  \
      (__attribute__((address_space(3))) void*)(l), 16, 0, 0)

#define MFMA16(a, b, c) __builtin_amdgcn_mfma_f32_16x16x32_bf16((a), (b), (c), 0, 0, 0)
#define MFMA32(a, b, c) __builtin_amdgcn_mfma_f32_32x32x16_bf16((a), (b), (c), 0, 0, 0)

static constexpr int kS = 4096;   // sequence length (64*64)
static constexpr int kD = 768;    // model dim
static constexpr int kNH = 12;    // heads
static constexpr int kHD = 64;    // head dim
static constexpr int kNE = 2304;  // 3*D

static __device__ __forceinline__ float bf2f(short s) {
  union { unsigned u; float f; } x;
  x.u = ((unsigned)(unsigned short)s) << 16;
  return x.f;
}

// ===================== Kernel 0: fp32 -> bf16 conversion (all 3 tensors) ===
static constexpr int kNX8 = kS * kD / 8;      // 393216
static constexpr int kNWq8 = kNE * kD / 8;    // 221184
static constexpr int kNWp8 = kD * kD / 8;     // 73728

__global__ __launch_bounds__(256)
void k_cvt3(const float* __restrict__ x, const float* __restrict__ wq,
            const float* __restrict__ wp, bf16* __restrict__ xb,
            bf16* __restrict__ wqb, bf16* __restrict__ wpb) {
  int i = blockIdx.x * 256 + threadIdx.x;
  const float* src;
  short* dst;
  if (i < kNX8) {
    src = x; dst = (short*)xb;
  } else if (i < kNX8 + kNWq8) {
    i -= kNX8; src = wq; dst = (short*)wqb;
  } else {
    i -= kNX8 + kNWq8; if (i >= kNWp8) return;
    src = wp; dst = (short*)wpb;
  }
  const f32x4 a = *(const f32x4*)(src + i * 8);
  const f32x4 b = *(const f32x4*)(src + i * 8 + 4);
  s16x8 o;
#pragma unroll
  for (int j = 0; j < 4; ++j) {
    o[j] = (short)__bfloat16_as_ushort(__float2bfloat16(a[j]));
    o[j + 4] = (short)__bfloat16_as_ushort(__float2bfloat16(b[j]));
  }
  *(s16x8*)(dst + i * 8) = o;
}

// ===================== Kernel 1: QKV GEMM (2-phase dbuf) ===================
__global__ __launch_bounds__(256, 2)
void k_qkv(const bf16* __restrict__ X, const bf16* __restrict__ W,
           bf16* __restrict__ Qw, bf16* __restrict__ Kw, bf16* __restrict__ Vw) {
  __shared__ __align__(16) short As[2][128 * 32];
  __shared__ __align__(16) short Bs[2][128 * 32];
  const int tid = threadIdx.x;
  const int wv = tid >> 6, ln = tid & 63;
  const int r = ln & 15, kq = ln >> 4;
  const int bm = blockIdx.x * 128;   // s
  const int bn = blockIdx.y * 128;   // e
  const int wr = wv >> 1, wc = wv & 1;
  const short* Xs = (const short*)X;
  const short* Ws = (const short*)W;

  f32x4 acc[4][4] = {};

  const int c0 = wv * 128 + ln, c1 = c0 + 64;
  const int ra0 = c0 >> 2, ka0 = c0 & 3;
  const int ra1 = c1 >> 2, ka1 = c1 & 3;
  const int off0 = wv * 1024, off1 = off0 + 512;
  const short* gA0 = Xs + (bm + ra0) * kD + ka0 * 8;
  const short* gA1 = Xs + (bm + ra1) * kD + ka1 * 8;
  const short* gB0 = Ws + (bn + ra0) * kD + ka0 * 8;
  const short* gB1 = Ws + (bn + ra1) * kD + ka1 * 8;

  GLD16(gA0, &As[0][off0]);
  GLD16(gA1, &As[0][off1]);
  GLD16(gB0, &Bs[0][off0]);
  GLD16(gB1, &Bs[0][off1]);
  __syncthreads();

  const int NT = kD / 32;  // 24
  for (int t = 0; t < NT; ++t) {
    const short* aCur = As[t & 1];
    const short* bCur = Bs[t & 1];
    if (t + 1 < NT) {
      const int k1 = (t + 1) * 32;
      short* aN = As[(t + 1) & 1];
      short* bN = Bs[(t + 1) & 1];
      GLD16(gA0 + k1, aN + off0);
      GLD16(gA1 + k1, aN + off1);
      GLD16(gB0 + k1, bN + off0);
      GLD16(gB1 + k1, bN + off1);
    }
    s16x8 a[4], b[4];
#pragma unroll
    for (int i = 0; i < 4; ++i)
      a[i] = *(const s16x8*)(aCur + (wr * 64 + i * 16 + r) * 32 + kq * 8);
#pragma unroll
    for (int j = 0; j < 4; ++j)
      b[j] = *(const s16x8*)(bCur + (wc * 64 + j * 16 + r) * 32 + kq * 8);
#pragma unroll
    for (int i = 0; i < 4; ++i)
#pragma unroll
      for (int j = 0; j < 4; ++j) acc[i][j] = MFMA16(a[i], b[j], acc[i][j]);
    __syncthreads();
  }

  const int which = bn / kD;
  bf16* dst = (which == 0) ? Qw : (which == 1) ? Kw : Vw;
  const float scl = (which == 0) ? 0.125f : 1.0f;  // hd^-0.5, exact pow2
  const int ebase = bn - which * kD + wc * 64;
#pragma unroll
  for (int j = 0; j < 4; ++j) {
    const int e = ebase + j * 16 + r;
    const int h = e >> 6, d = e & 63;
#pragma unroll
    for (int i = 0; i < 4; ++i) {
      const int srow = bm + wr * 64 + i * 16 + kq * 4;
#pragma unroll
      for (int rr = 0; rr < 4; ++rr)
        dst[(h * kS + srow + rr) * kHD + d] = __float2bfloat16(acc[i][j][rr] * scl);
    }
  }
}

// ===================== Kernel 2: V transpose ===============================
__global__ __launch_bounds__(256, 2)
void k_vt(const bf16* __restrict__ Vw, bf16* __restrict__ Vt) {
  __shared__ __align__(16) short L[64 * 72];
  const int h = blockIdx.y, st = blockIdx.x;
  const int t = threadIdx.x;
  const short* src = (const short*)Vw + (h * kS + st * 64) * kHD;
  short* dstb = (short*)Vt + h * kHD * kS;
#pragma unroll
  for (int u = 0; u < 2; ++u) {
    const int c = u * 256 + t;
    const int row = c >> 3, ch = c & 7;
    *(s16x8*)(L + row * 72 + ch * 8) = *(const s16x8*)(src + row * kHD + ch * 8);
  }
  __syncthreads();
#pragma unroll
  for (int u = 0; u < 2; ++u) {
    const int c = u * 256 + t;
    const int d = c >> 3, ch = c & 7;
    s16x8 v;
#pragma unroll
    for (int j = 0; j < 8; ++j) v[j] = L[(ch * 8 + j) * 72 + d];
    *(s16x8*)(dstb + d * kS + st * 64 + ch * 8) = v;
  }
}

// ===================== Kernel 3: flash attention, kv-split across BLOCKS ===
// Grid 1536: each block = (head, 64-q-tile, kv-HALF of 2048 rows = 32 tiles).
// No-max softmax -> partials additive: block writes unnormalized partial O
// (bf16) + row sums (fp32); k_comb combines. Purpose: break the structural
// 3-blocks/CU grid cap (768/256) that pinned occupancy at 12 waves/CU --
// rounds 6/9/10 showed no pipe >50% (latency/dependency-bound), so TLP is
// the lever. LDS 32KB (single-tile K+V dbuf) -> 5 blocks/CU resident.
// Math = round-10 body + round-11-verified permlane32_swap. K back in LDS
// (round 11 lesson: per-lane 128B-stride global K loads are uncoalesced).
__global__ __launch_bounds__(256, 5)
void k_attn(const bf16* __restrict__ Qw, const bf16* __restrict__ Kw,
            const bf16* __restrict__ Vt, bf16* __restrict__ Opart,
            float* __restrict__ Lpart) {
  __shared__ __align__(16) short Ks[2][64 * 64];  // [kv][d], swizzled chunks
  __shared__ __align__(16) short Vs[2][64 * 64];  // [d][kv], swizzled chunks
  const int tid = threadIdx.x;
  const int wv = tid >> 6, ln = tid & 63;
  const int qh = wv >> 1;    // q-subtile (32 rows)
  const int kvh = wv & 1;    // kv-half of each 64-tile (within block's range)
  const int col = ln & 31;
  const int lh = ln >> 5;

  // XCD-pair grouping (bijective): wg -> (pair p, b in [0,384));
  // b -> (hh 3/pair, qb, half). Both halves of (hh,qb) on one XCD pair.
  const int wg = blockIdx.x;
  const int p = (wg & 7) >> 1;
  const int b = ((wg >> 3) << 1) | (wg & 1);      // 0..383
  const int hh = 3 * p + (b >> 7);
  const int rem = b & 127;
  const int qb = rem >> 1;
  const int half = rem & 1;
  const int q0 = qb * 64;
  const int pidx = (hh * 64 + qb) * 2 + half;

  const short* Qh = (const short*)Qw + ((size_t)hh * kS + q0 + qh * 32) * kHD;
  const short* Kh = (const short*)Kw + (size_t)hh * kS * kHD + (size_t)half * 2048 * kHD;
  const short* Vh = (const short*)Vt + (size_t)hh * kHD * kS + half * 2048;

  // Q as B-operand frags: col = q (ln&31), k = kb*16 + lh*8 + {0..7}
  s16x8 bq[4];
#pragma unroll
  for (int kb = 0; kb < 4; ++kb)
    bq[kb] = *(const s16x8*)(Qh + col * kHD + kb * 16 + lh * 8);

  f32x16 o[2] = {};  // partial O[32q][64d] over this wave's kv share
  float lp = 0.f;

  // staging: 256 threads x 2 chunks per tensor; source-side XOR swizzle
  int ldso[2];
  const short* gK[2];
  const short* gV[2];
#pragma unroll
  for (int u = 0; u < 2; ++u) {
    const int c = u * 256 + tid;
    const int kr = c >> 3, g = (c & 7) ^ (kr & 7);
    ldso[u] = c * 8;
    gK[u] = Kh + kr * kHD + g * 8;
    gV[u] = Vh + kr * kS + g * 8;
  }

#pragma unroll
  for (int u = 0; u < 2; ++u) {
    GLD16(gK[u], &Ks[0][ldso[u]]);
    GLD16(gV[u], &Vs[0][ldso[u]]);
  }
  __syncthreads();

  const int NT2 = 32;  // this block's 32 kv tiles (2048 rows)
  for (int kt = 0; kt < NT2; ++kt) {
    const short* ksCur = Ks[kt & 1];
    const short* vsCur = Vs[kt & 1];
    if (kt + 1 < NT2) {
      short* ksN = Ks[(kt + 1) & 1];
      short* vsN = Vs[(kt + 1) & 1];
      const int dk = (kt + 1) * 64 * kHD;
      const int dv = (kt + 1) * 64;
#pragma unroll
      for (int u = 0; u < 2; ++u) {
        GLD16(gK[u] + dk, ksN + ldso[u]);
        GLD16(gV[u] + dv, vsN + ldso[u]);
      }
    }

    // --- QK^T (swapped) for this wave's kv-half ---
    f32x16 z = {};
    const int krow = kvh * 32 + col;
    const int ksw = krow & 7;
    __builtin_amdgcn_s_setprio(1);
#pragma unroll
    for (int kb = 0; kb < 4; ++kb) {
      const int ch = ((kb << 1) + lh) ^ ksw;
      s16x8 ak = *(const s16x8*)(ksCur + krow * 64 + ch * 8);
      z = MFMA32(ak, bq[kb], z);
    }
    __builtin_amdgcn_s_setprio(0);

    // --- P = exp(S); pack bf16 pairs (proven scalar RNE path) ---
    float pv[16];
#pragma unroll
    for (int g = 0; g < 16; ++g) {
      pv[g] = __expf(z[g]);
      lp += pv[g];
    }
    unsigned own[8];
#pragma unroll
    for (int m = 0; m < 4; ++m) {
      own[2 * m] = (unsigned)__bfloat16_as_ushort(__float2bfloat16(pv[4 * m])) |
                   ((unsigned)__bfloat16_as_ushort(__float2bfloat16(pv[4 * m + 1])) << 16);
      own[2 * m + 1] = (unsigned)__bfloat16_as_ushort(__float2bfloat16(pv[4 * m + 2])) |
                       ((unsigned)__bfloat16_as_ushort(__float2bfloat16(pv[4 * m + 3])) << 16);
    }

    // --- PV: A-frags via permlane32_swap (round-11 verified) ---
    __builtin_amdgcn_s_setprio(1);
#pragma unroll
    for (int kvk = 0; kvk < 2; ++kvk) {
      u32x2 sA = __builtin_amdgcn_permlane32_swap(own[4 * kvk + 0], own[4 * kvk + 2], false, false);
      u32x2 sB = __builtin_amdgcn_permlane32_swap(own[4 * kvk + 1], own[4 * kvk + 3], false, false);
      u32x4 apv;
      apv[0] = sA[0];
      apv[1] = sB[0];
      apv[2] = sA[1];
      apv[3] = sB[1];
      const s16x8 ap = __builtin_bit_cast(s16x8, apv);
      const int kvg = kvh * 2 + kvk;
#pragma unroll
      for (int db = 0; db < 2; ++db) {
        const int vrow = db * 32 + col;
        const int ch = ((kvg << 1) + lh) ^ (vrow & 7);
        s16x8 vb = *(const s16x8*)(vsCur + vrow * 64 + ch * 8);
        o[db] = MFMA32(ap, vb, o[db]);
      }
    }
    __builtin_amdgcn_s_setprio(0);
    __syncthreads();
  }

  // --- combine kvh waves through (now-dead) LDS; write UNNORMALIZED partial
  lp += __shfl_xor(lp, 32);           // add other lh's kv rows within wave
  float* Of = (float*)Ks;             // [64 q][64 d] fp32 = 16 KB
  float* Lf = (float*)Vs;             // [64 q] row sums

  if (kvh == 1) {
#pragma unroll
    for (int db = 0; db < 2; ++db)
#pragma unroll
      for (int g = 0; g < 16; ++g) {
        const int qoff = (g & 3) + 8 * (g >> 2) + 4 * lh;
        Of[(qh * 32 + qoff) * 64 + db * 32 + col] = o[db][g];
      }
    if (lh == 0) Lf[qh * 32 + col] = lp;
  }
  __syncthreads();
  if (kvh == 0) {
    lp += Lf[qh * 32 + col];
    if (lh == 0) Lpart[pidx * 64 + qh * 32 + col] = lp;
    short* Ob = (short*)Opart + (size_t)pidx * 4096;
#pragma unroll
    for (int db = 0; db < 2; ++db)
#pragma unroll
      for (int g = 0; g < 16; ++g) {
        const int qoff = (g & 3) + 8 * (g >> 2) + 4 * lh;
        const float val = o[db][g] + Of[(qh * 32 + qoff) * 64 + db * 32 + col];
        Ob[(qh * 32 + qoff) * 64 + db * 32 + col] =
            (short)__bfloat16_as_ushort(__float2bfloat16(val));
      }
  }
}

// ===================== Kernel 3b: partial combine ==========================
// one block per (hh, qb): Att[s][h*64+d] = (O0+O1) / (l0+l1)
__global__ __launch_bounds__(256)
void k_comb(const bf16* __restrict__ Opart, const float* __restrict__ Lpart,
            bf16* __restrict__ Att) {
  const int blk = blockIdx.x;          // hh*64 + qb
  const int hh = blk >> 6, qb = blk & 63;
  const int t = threadIdx.x;
  const int q = t >> 2;                // 0..63
  const int dg = t & 3;                // 16 d-elems each
  const float inv =
      1.0f / (Lpart[(blk * 2 + 0) * 64 + q] + Lpart[(blk * 2 + 1) * 64 + q]);
  const short* p0 = (const short*)Opart + ((size_t)blk * 2 + 0) * 4096 + q * 64 + dg * 16;
  const short* p1 = (const short*)Opart + ((size_t)blk * 2 + 1) * 4096 + q * 64 + dg * 16;
  short* dst = (short*)Att + (size_t)(qb * 64 + q) * kD + hh * kHD + dg * 16;
#pragma unroll
  for (int j = 0; j < 2; ++j) {
    const s16x8 a = *(const s16x8*)(p0 + j * 8);
    const s16x8 bvv = *(const s16x8*)(p1 + j * 8);
    s16x8 r;
#pragma unroll
    for (int e = 0; e < 8; ++e) {
      const float v = (bf2f(a[e]) + bf2f(bvv[e])) * inv;
      r[e] = (short)__bfloat16_as_ushort(__float2bfloat16(v));
    }
    *(s16x8*)(dst + j * 8) = r;
  }
}

// ===================== Kernel 4: output projection (64x64 tiles, dbuf) =====
__global__ __launch_bounds__(256, 3)
void k_proj(const bf16* __restrict__ A, const bf16* __restrict__ W,
            const float* __restrict__ Bias, float* __restrict__ Out) {
  __shared__ __align__(16) short As[2][64 * 32];
  __shared__ __align__(16) short Bs[2][64 * 32];
  const int tid = threadIdx.x;
  const int wv = tid >> 6, ln = tid & 63;
  const int r = ln & 15, kq = ln >> 4;
  const int bm = blockIdx.x * 64;
  const int bn = blockIdx.y * 64;
  const int wr = wv >> 1, wc = wv & 1;
  const short* Asrc = (const short*)A;
  const short* Wsrc = (const short*)W;

  f32x4 acc[2][2] = {};
  const int c = wv * 64 + ln;
  const int ra = c >> 2, ka = c & 3;
  const int off = wv * 512;
  const short* gA = Asrc + (bm + ra) * kD + ka * 8;
  const short* gB = Wsrc + (bn + ra) * kD + ka * 8;

  GLD16(gA, &As[0][off]);
  GLD16(gB, &Bs[0][off]);
  __syncthreads();

  const int NT = kD / 32;  // 24
  for (int t = 0; t < NT; ++t) {
    const short* aCur = As[t & 1];
    const short* bCur = Bs[t & 1];
    if (t + 1 < NT) {
      const int k1 = (t + 1) * 32;
      GLD16(gA + k1, &As[(t + 1) & 1][off]);
      GLD16(gB + k1, &Bs[(t + 1) & 1][off]);
    }
    s16x8 a[2], b[2];
#pragma unroll
    for (int i = 0; i < 2; ++i)
      a[i] = *(const s16x8*)(aCur + (wr * 32 + i * 16 + r) * 32 + kq * 8);
#pragma unroll
    for (int j = 0; j < 2; ++j)
      b[j] = *(const s16x8*)(bCur + (wc * 32 + j * 16 + r) * 32 + kq * 8);
#pragma unroll
    for (int i = 0; i < 2; ++i)
#pragma unroll
      for (int j = 0; j < 2; ++j) acc[i][j] = MFMA16(a[i], b[j], acc[i][j]);
    __syncthreads();
  }
#pragma unroll
  for (int j = 0; j < 2; ++j) {
    const int e = bn + wc * 32 + j * 16 + r;
    const float bv = Bias[e];
#pragma unroll
    for (int i = 0; i < 2; ++i) {
      const int srow = bm + wr * 32 + i * 16 + kq * 4;
#pragma unroll
      for (int rr = 0; rr < 4; ++rr)
        Out[(srow + rr) * kD + e] = acc[i][j][rr] + bv;
    }
  }
}

// ===================== launcher ============================================
extern "C" void kernel_launch(void* const* d_in, const int* in_sizes, int n_in,
                              void* d_out, int out_size, void* d_ws, size_t ws_size,
                              hipStream_t stream) {
  const float* x = (const float*)d_in[0];
  const float* w_qkv = (const float*)d_in[1];
  const float* w_proj = (const float*)d_in[2];
  const float* b_proj = (const float*)d_in[3];
  float* out = (float*)d_out;

  const size_t HS = (size_t)kNH * kS * kHD;  // 3,145,728 elems per tensor
  const int nX = kS * kD;
  const int nWq = kNE * kD;
  const int nWp = kD * kD;

  // Layout (reordered so Xb|Wqb|Vw are contiguous and dead by attn time --
  // aliased by the flash-decoding partial buffers):
  bf16* Xb = (bf16*)d_ws;            // x as bf16          [s][d]      (dead after k_qkv)
  bf16* Wqb = Xb + nX;               // w_qkv as bf16      [e][d]      (dead after k_qkv)
  bf16* Vw = Wqb + nWq;              // v                  [h][s][d]   (dead after k_vt)
  bf16* Wpb = Vw + HS;               // w_proj as bf16     [e][d]
  bf16* Qw = Wpb + nWp;              // q (pre-scaled)     [h][s][d]
  bf16* Kw = Qw + HS;                // k                  [h][s][d]
  bf16* Vt = Kw + HS;                // v transposed       [h][d][s]
  bf16* At = Vt + HS;                // attention output   [s][h*64+d]
  // partials alias the dead region: 1536*4096 bf16 (12.58MB) + 98304 f32
  bf16* Opart = (bf16*)d_ws;
  float* Lpart = (float*)((short*)d_ws + (size_t)1536 * 4096);
  // Opart+Lpart end at 12.97MB < Xb+Wqb+Vw = 16.12MB  ✓

  const int totalC = kNX8 + kNWq8 + kNWp8;
  k_cvt3<<<(totalC + 255) / 256, 256, 0, stream>>>(x, w_qkv, w_proj, Xb, Wqb, Wpb);

  k_qkv<<<dim3(kS / 128, kNE / 128), 256, 0, stream>>>(Xb, Wqb, Qw, Kw, Vw);
  k_vt<<<dim3(kS / 64, kNH), 256, 0, stream>>>(Vw, Vt);
  k_attn<<<dim3(2 * (kS / 64) * kNH), 256, 0, stream>>>(Qw, Kw, Vt, Opart, Lpart);
  k_comb<<<dim3((kS / 64) * kNH), 256, 0, stream>>>(Opart, Lpart, At);
  k_proj<<<dim3(kS / 64, kD / 64), 256, 0, stream>>>(At, Wpb, b_proj, out);
}

// Round 14
// 132.988 us; speedup vs baseline: 1.1871x; 1.0004x over previous
//
#include <hip/hip_runtime.h>
#include <hip/hip_bf16.h>
#include <math.h>

typedef short s16x8 __attribute__((ext_vector_type(8)));
typedef unsigned u32x2 __attribute__((ext_vector_type(2)));
typedef unsigned u32x4 __attribute__((ext_vector_type(4)));
typedef float f32x4 __attribute__((ext_vector_type(4)));
typedef float f32x16 __attribute__((ext_vector_type(16)));
typedef __hip_bfloat16 bf16;

#define GLD16(g, l)                                                        \
  __builtin_amdgcn_global_load_lds(                                        \
      (const __attribute__((address_space(1))) void*)(g),                  \
      (__attribute__((address_space(3))) void*)(l), 16, 0, 0)

#define MFMA16(a, b, c) __builtin_amdgcn_mfma_f32_16x16x32_bf16((a), (b), (c), 0, 0, 0)
#define MFMA32(a, b, c) __builtin_amdgcn_mfma_f32_32x32x16_bf16((a), (b), (c), 0, 0, 0)

static constexpr int kS = 4096;   // sequence length (64*64)
static constexpr int kD = 768;    // model dim
static constexpr int kNH = 12;    // heads
static constexpr int kHD = 64;    // head dim
static constexpr int kNE = 2304;  // 3*D

static __device__ __forceinline__ float bf2f(short s) {
  union { unsigned u; float f; } x;
  x.u = ((unsigned)(unsigned short)s) << 16;
  return x.f;
}

// packed f32 pair -> bf16x2 word via documented HIP intrinsic (RNE).
// low 16 bits = first value (matches the proven own[] layout).
// (.x/.y extracted via __bfloat16_as_ushort -- bf162 is not trivially
// copyable so __builtin_bit_cast is rejected; the or/shift folds away if
// the intrinsic lowers to a packed cvt.)
static __device__ __forceinline__ unsigned pk_bf16(float lo, float hi) {
  float2 f2;
  f2.x = lo;
  f2.y = hi;
  __hip_bfloat162 h2 = __float22bfloat162_rn(f2);
  return (unsigned)__bfloat16_as_ushort(h2.x) |
         ((unsigned)__bfloat16_as_ushort(h2.y) << 16);
}

// ===================== Kernel 0: fp32 -> bf16 conversion (all 3 tensors) ===
static constexpr int kNX8 = kS * kD / 8;      // 393216
static constexpr int kNWq8 = kNE * kD / 8;    // 221184
static constexpr int kNWp8 = kD * kD / 8;     // 73728

__global__ __launch_bounds__(256)
void k_cvt3(const float* __restrict__ x, const float* __restrict__ wq,
            const float* __restrict__ wp, bf16* __restrict__ xb,
            bf16* __restrict__ wqb, bf16* __restrict__ wpb) {
  int i = blockIdx.x * 256 + threadIdx.x;
  const float* src;
  short* dst;
  if (i < kNX8) {
    src = x; dst = (short*)xb;
  } else if (i < kNX8 + kNWq8) {
    i -= kNX8; src = wq; dst = (short*)wqb;
  } else {
    i -= kNX8 + kNWq8; if (i >= kNWp8) return;
    src = wp; dst = (short*)wpb;
  }
  const f32x4 a = *(const f32x4*)(src + i * 8);
  const f32x4 b = *(const f32x4*)(src + i * 8 + 4);
  s16x8 o;
#pragma unroll
  for (int j = 0; j < 4; ++j) {
    o[j] = (short)__bfloat16_as_ushort(__float2bfloat16(a[j]));
    o[j + 4] = (short)__bfloat16_as_ushort(__float2bfloat16(b[j]));
  }
  *(s16x8*)(dst + i * 8) = o;
}

// ===================== Kernel 1: QKV GEMM (2-phase dbuf) ===================
__global__ __launch_bounds__(256, 2)
void k_qkv(const bf16* __restrict__ X, const bf16* __restrict__ W,
           bf16* __restrict__ Qw, bf16* __restrict__ Kw, bf16* __restrict__ Vw) {
  __shared__ __align__(16) short As[2][128 * 32];
  __shared__ __align__(16) short Bs[2][128 * 32];
  const int tid = threadIdx.x;
  const int wv = tid >> 6, ln = tid & 63;
  const int r = ln & 15, kq = ln >> 4;
  const int bm = blockIdx.x * 128;   // s
  const int bn = blockIdx.y * 128;   // e
  const int wr = wv >> 1, wc = wv & 1;
  const short* Xs = (const short*)X;
  const short* Ws = (const short*)W;

  f32x4 acc[4][4] = {};

  const int c0 = wv * 128 + ln, c1 = c0 + 64;
  const int ra0 = c0 >> 2, ka0 = c0 & 3;
  const int ra1 = c1 >> 2, ka1 = c1 & 3;
  const int off0 = wv * 1024, off1 = off0 + 512;
  const short* gA0 = Xs + (bm + ra0) * kD + ka0 * 8;
  const short* gA1 = Xs + (bm + ra1) * kD + ka1 * 8;
  const short* gB0 = Ws + (bn + ra0) * kD + ka0 * 8;
  const short* gB1 = Ws + (bn + ra1) * kD + ka1 * 8;

  GLD16(gA0, &As[0][off0]);
  GLD16(gA1, &As[0][off1]);
  GLD16(gB0, &Bs[0][off0]);
  GLD16(gB1, &Bs[0][off1]);
  __syncthreads();

  const int NT = kD / 32;  // 24
  for (int t = 0; t < NT; ++t) {
    const short* aCur = As[t & 1];
    const short* bCur = Bs[t & 1];
    if (t + 1 < NT) {
      const int k1 = (t + 1) * 32;
      short* aN = As[(t + 1) & 1];
      short* bN = Bs[(t + 1) & 1];
      GLD16(gA0 + k1, aN + off0);
      GLD16(gA1 + k1, aN + off1);
      GLD16(gB0 + k1, bN + off0);
      GLD16(gB1 + k1, bN + off1);
    }
    s16x8 a[4], b[4];
#pragma unroll
    for (int i = 0; i < 4; ++i)
      a[i] = *(const s16x8*)(aCur + (wr * 64 + i * 16 + r) * 32 + kq * 8);
#pragma unroll
    for (int j = 0; j < 4; ++j)
      b[j] = *(const s16x8*)(bCur + (wc * 64 + j * 16 + r) * 32 + kq * 8);
#pragma unroll
    for (int i = 0; i < 4; ++i)
#pragma unroll
      for (int j = 0; j < 4; ++j) acc[i][j] = MFMA16(a[i], b[j], acc[i][j]);
    __syncthreads();
  }

  const int which = bn / kD;
  bf16* dst = (which == 0) ? Qw : (which == 1) ? Kw : Vw;
  const float scl = (which == 0) ? 0.125f : 1.0f;  // hd^-0.5, exact pow2
  const int ebase = bn - which * kD + wc * 64;
#pragma unroll
  for (int j = 0; j < 4; ++j) {
    const int e = ebase + j * 16 + r;
    const int h = e >> 6, d = e & 63;
#pragma unroll
    for (int i = 0; i < 4; ++i) {
      const int srow = bm + wr * 64 + i * 16 + kq * 4;
#pragma unroll
      for (int rr = 0; rr < 4; ++rr)
        dst[(h * kS + srow + rr) * kHD + d] = __float2bfloat16(acc[i][j][rr] * scl);
    }
  }
}

// ===================== Kernel 2: V transpose ===============================
__global__ __launch_bounds__(256, 2)
void k_vt(const bf16* __restrict__ Vw, bf16* __restrict__ Vt) {
  __shared__ __align__(16) short L[64 * 72];
  const int h = blockIdx.y, st = blockIdx.x;
  const int t = threadIdx.x;
  const short* src = (const short*)Vw + (h * kS + st * 64) * kHD;
  short* dstb = (short*)Vt + h * kHD * kS;
#pragma unroll
  for (int u = 0; u < 2; ++u) {
    const int c = u * 256 + t;
    const int row = c >> 3, ch = c & 7;
    *(s16x8*)(L + row * 72 + ch * 8) = *(const s16x8*)(src + row * kHD + ch * 8);
  }
  __syncthreads();
#pragma unroll
  for (int u = 0; u < 2; ++u) {
    const int c = u * 256 + t;
    const int d = c >> 3, ch = c & 7;
    s16x8 v;
#pragma unroll
    for (int j = 0; j < 8; ++j) v[j] = L[(ch * 8 + j) * 72 + d];
    *(s16x8*)(dstb + d * kS + st * 64 + ch * 8) = v;
  }
}

// ===================== Kernel 3: flash attention, kv-split across BLOCKS ===
// Structure = round 12 (proven, 83.8us). ONE isolated change: the P->bf16
// pack uses __float22bfloat162_rn (documented HIP intrinsic; should lower
// to native v_cvt_pk_bf16_f32) instead of 16 software-RNE scalar casts +
// 8 or/shift -- the largest VALU block (~70 of ~180 ops/iter; VALUBusy 55%
// is the pacer). NOT inline asm (rounds 7/8 hazard lesson).
__global__ __launch_bounds__(256, 5)
void k_attn(const bf16* __restrict__ Qw, const bf16* __restrict__ Kw,
            const bf16* __restrict__ Vt, bf16* __restrict__ Opart,
            float* __restrict__ Lpart) {
  __shared__ __align__(16) short Ks[2][64 * 64];  // [kv][d], swizzled chunks
  __shared__ __align__(16) short Vs[2][64 * 64];  // [d][kv], swizzled chunks
  const int tid = threadIdx.x;
  const int wv = tid >> 6, ln = tid & 63;
  const int qh = wv >> 1;    // q-subtile (32 rows)
  const int kvh = wv & 1;    // kv-half of each 64-tile (within block's range)
  const int col = ln & 31;
  const int lh = ln >> 5;

  // XCD-pair grouping (bijective): wg -> (pair p, b in [0,384));
  // b -> (hh 3/pair, qb, half). Both halves of (hh,qb) on one XCD pair.
  const int wg = blockIdx.x;
  const int p = (wg & 7) >> 1;
  const int b = ((wg >> 3) << 1) | (wg & 1);      // 0..383
  const int hh = 3 * p + (b >> 7);
  const int rem = b & 127;
  const int qb = rem >> 1;
  const int half = rem & 1;
  const int q0 = qb * 64;
  const int pidx = (hh * 64 + qb) * 2 + half;

  const short* Qh = (const short*)Qw + ((size_t)hh * kS + q0 + qh * 32) * kHD;
  const short* Kh = (const short*)Kw + (size_t)hh * kS * kHD + (size_t)half * 2048 * kHD;
  const short* Vh = (const short*)Vt + (size_t)hh * kHD * kS + half * 2048;

  // Q as B-operand frags: col = q (ln&31), k = kb*16 + lh*8 + {0..7}
  s16x8 bq[4];
#pragma unroll
  for (int kb = 0; kb < 4; ++kb)
    bq[kb] = *(const s16x8*)(Qh + col * kHD + kb * 16 + lh * 8);

  f32x16 o[2] = {};  // partial O[32q][64d] over this wave's kv share
  float lp = 0.f;

  // staging: 256 threads x 2 chunks per tensor; source-side XOR swizzle
  int ldso[2];
  const short* gK[2];
  const short* gV[2];
#pragma unroll
  for (int u = 0; u < 2; ++u) {
    const int c = u * 256 + tid;
    const int kr = c >> 3, g = (c & 7) ^ (kr & 7);
    ldso[u] = c * 8;
    gK[u] = Kh + kr * kHD + g * 8;
    gV[u] = Vh + kr * kS + g * 8;
  }

#pragma unroll
  for (int u = 0; u < 2; ++u) {
    GLD16(gK[u], &Ks[0][ldso[u]]);
    GLD16(gV[u], &Vs[0][ldso[u]]);
  }
  __syncthreads();

  const int NT2 = 32;  // this block's 32 kv tiles (2048 rows)
  for (int kt = 0; kt < NT2; ++kt) {
    const short* ksCur = Ks[kt & 1];
    const short* vsCur = Vs[kt & 1];
    if (kt + 1 < NT2) {
      short* ksN = Ks[(kt + 1) & 1];
      short* vsN = Vs[(kt + 1) & 1];
      const int dk = (kt + 1) * 64 * kHD;
      const int dv = (kt + 1) * 64;
#pragma unroll
      for (int u = 0; u < 2; ++u) {
        GLD16(gK[u] + dk, ksN + ldso[u]);
        GLD16(gV[u] + dv, vsN + ldso[u]);
      }
    }

    // --- QK^T (swapped) for this wave's kv-half ---
    f32x16 z = {};
    const int krow = kvh * 32 + col;
    const int ksw = krow & 7;
    __builtin_amdgcn_s_setprio(1);
#pragma unroll
    for (int kb = 0; kb < 4; ++kb) {
      const int ch = ((kb << 1) + lh) ^ ksw;
      s16x8 ak = *(const s16x8*)(ksCur + krow * 64 + ch * 8);
      z = MFMA32(ak, bq[kb], z);
    }
    __builtin_amdgcn_s_setprio(0);

    // --- P = exp(S); packed RNE bf16 conversion (the round-13 change) ---
    float pv[16];
#pragma unroll
    for (int g = 0; g < 16; ++g) {
      pv[g] = __expf(z[g]);
      lp += pv[g];
    }
    unsigned own[8];
#pragma unroll
    for (int m = 0; m < 8; ++m)
      own[m] = pk_bf16(pv[2 * m], pv[2 * m + 1]);

    // --- PV: A-frags via permlane32_swap (round-11 verified) ---
    __builtin_amdgcn_s_setprio(1);
#pragma unroll
    for (int kvk = 0; kvk < 2; ++kvk) {
      u32x2 sA = __builtin_amdgcn_permlane32_swap(own[4 * kvk + 0], own[4 * kvk + 2], false, false);
      u32x2 sB = __builtin_amdgcn_permlane32_swap(own[4 * kvk + 1], own[4 * kvk + 3], false, false);
      u32x4 apv;
      apv[0] = sA[0];
      apv[1] = sB[0];
      apv[2] = sA[1];
      apv[3] = sB[1];
      const s16x8 ap = __builtin_bit_cast(s16x8, apv);
      const int kvg = kvh * 2 + kvk;
#pragma unroll
      for (int db = 0; db < 2; ++db) {
        const int vrow = db * 32 + col;
        const int ch = ((kvg << 1) + lh) ^ (vrow & 7);
        s16x8 vb = *(const s16x8*)(vsCur + vrow * 64 + ch * 8);
        o[db] = MFMA32(ap, vb, o[db]);
      }
    }
    __builtin_amdgcn_s_setprio(0);
    __syncthreads();
  }

  // --- combine kvh waves through (now-dead) LDS; write UNNORMALIZED partial
  lp += __shfl_xor(lp, 32);           // add other lh's kv rows within wave
  float* Of = (float*)Ks;             // [64 q][64 d] fp32 = 16 KB
  float* Lf = (float*)Vs;             // [64 q] row sums

  if (kvh == 1) {
#pragma unroll
    for (int db = 0; db < 2; ++db)
#pragma unroll
      for (int g = 0; g < 16; ++g) {
        const int qoff = (g & 3) + 8 * (g >> 2) + 4 * lh;
        Of[(qh * 32 + qoff) * 64 + db * 32 + col] = o[db][g];
      }
    if (lh == 0) Lf[qh * 32 + col] = lp;
  }
  __syncthreads();
  if (kvh == 0) {
    lp += Lf[qh * 32 + col];
    if (lh == 0) Lpart[pidx * 64 + qh * 32 + col] = lp;
    short* Ob = (short*)Opart + (size_t)pidx * 4096;
#pragma unroll
    for (int db = 0; db < 2; ++db)
#pragma unroll
      for (int g = 0; g < 16; ++g) {
        const int qoff = (g & 3) + 8 * (g >> 2) + 4 * lh;
        const float val = o[db][g] + Of[(qh * 32 + qoff) * 64 + db * 32 + col];
        Ob[(qh * 32 + qoff) * 64 + db * 32 + col] =
            (short)__bfloat16_as_ushort(__float2bfloat16(val));
      }
  }
}

// ===================== Kernel 3b: partial combine ==========================
// one block per (hh, qb): Att[s][h*64+d] = (O0+O1) / (l0+l1)
__global__ __launch_bounds__(256)
void k_comb(const bf16* __restrict__ Opart, const float* __restrict__ Lpart,
            bf16* __restrict__ Att) {
  const int blk = blockIdx.x;          // hh*64 + qb
  const int hh = blk >> 6, qb = blk & 63;
  const int t = threadIdx.x;
  const int q = t >> 2;                // 0..63
  const int dg = t & 3;                // 16 d-elems each
  const float inv =
      1.0f / (Lpart[(blk * 2 + 0) * 64 + q] + Lpart[(blk * 2 + 1) * 64 + q]);
  const short* p0 = (const short*)Opart + ((size_t)blk * 2 + 0) * 4096 + q * 64 + dg * 16;
  const short* p1 = (const short*)Opart + ((size_t)blk * 2 + 1) * 4096 + q * 64 + dg * 16;
  short* dst = (short*)Att + (size_t)(qb * 64 + q) * kD + hh * kHD + dg * 16;
#pragma unroll
  for (int j = 0; j < 2; ++j) {
    const s16x8 a = *(const s16x8*)(p0 + j * 8);
    const s16x8 bvv = *(const s16x8*)(p1 + j * 8);
    s16x8 r;
#pragma unroll
    for (int e = 0; e < 8; ++e) {
      const float v = (bf2f(a[e]) + bf2f(bvv[e])) * inv;
      r[e] = (short)__bfloat16_as_ushort(__float2bfloat16(v));
    }
    *(s16x8*)(dst + j * 8) = r;
  }
}

// ===================== Kernel 4: output projection (64x64 tiles, dbuf) =====
__global__ __launch_bounds__(256, 3)
void k_proj(const bf16* __restrict__ A, const bf16* __restrict__ W,
            const float* __restrict__ Bias, float* __restrict__ Out) {
  __shared__ __align__(16) short As[2][64 * 32];
  __shared__ __align__(16) short Bs[2][64 * 32];
  const int tid = threadIdx.x;
  const int wv = tid >> 6, ln = tid & 63;
  const int r = ln & 15, kq = ln >> 4;
  const int bm = blockIdx.x * 64;
  const int bn = blockIdx.y * 64;
  const int wr = wv >> 1, wc = wv & 1;
  const short* Asrc = (const short*)A;
  const short* Wsrc = (const short*)W;

  f32x4 acc[2][2] = {};
  const int c = wv * 64 + ln;
  const int ra = c >> 2, ka = c & 3;
  const int off = wv * 512;
  const short* gA = Asrc + (bm + ra) * kD + ka * 8;
  const short* gB = Wsrc + (bn + ra) * kD + ka * 8;

  GLD16(gA, &As[0][off]);
  GLD16(gB, &Bs[0][off]);
  __syncthreads();

  const int NT = kD / 32;  // 24
  for (int t = 0; t < NT; ++t) {
    const short* aCur = As[t & 1];
    const short* bCur = Bs[t & 1];
    if (t + 1 < NT) {
      const int k1 = (t + 1) * 32;
      GLD16(gA + k1, &As[(t + 1) & 1][off]);
      GLD16(gB + k1, &Bs[(t + 1) & 1][off]);
    }
    s16x8 a[2], b[2];
#pragma unroll
    for (int i = 0; i < 2; ++i)
      a[i] = *(const s16x8*)(aCur + (wr * 32 + i * 16 + r) * 32 + kq * 8);
#pragma unroll
    for (int j = 0; j < 2; ++j)
      b[j] = *(const s16x8*)(bCur + (wc * 32 + j * 16 + r) * 32 + kq * 8);
#pragma unroll
    for (int i = 0; i < 2; ++i)
#pragma unroll
      for (int j = 0; j < 2; ++j) acc[i][j] = MFMA16(a[i], b[j], acc[i][j]);
    __syncthreads();
  }
#pragma unroll
  for (int j = 0; j < 2; ++j) {
    const int e = bn + wc * 32 + j * 16 + r;
    const float bv = Bias[e];
#pragma unroll
    for (int i = 0; i < 2; ++i) {
      const int srow = bm + wr * 32 + i * 16 + kq * 4;
#pragma unroll
      for (int rr = 0; rr < 4; ++rr)
        Out[(srow + rr) * kD + e] = acc[i][j][rr] + bv;
    }
  }
}

// ===================== launcher ============================================
extern "C" void kernel_launch(void* const* d_in, const int* in_sizes, int n_in,
                              void* d_out, int out_size, void* d_ws, size_t ws_size,
                              hipStream_t stream) {
  const float* x = (const float*)d_in[0];
  const float* w_qkv = (const float*)d_in[1];
  const float* w_proj = (const float*)d_in[2];
  const float* b_proj = (const float*)d_in[3];
  float* out = (float*)d_out;

  const size_t HS = (size_t)kNH * kS * kHD;  // 3,145,728 elems per tensor
  const int nX = kS * kD;
  const int nWq = kNE * kD;
  const int nWp = kD * kD;

  // Layout (Xb|Wqb|Vw contiguous and dead by attn time -- aliased by the
  // flash-decoding partial buffers):
  bf16* Xb = (bf16*)d_ws;            // x as bf16          [s][d]      (dead after k_qkv)
  bf16* Wqb = Xb + nX;               // w_qkv as bf16      [e][d]      (dead after k_qkv)
  bf16* Vw = Wqb + nWq;              // v                  [h][s][d]   (dead after k_vt)
  bf16* Wpb = Vw + HS;               // w_proj as bf16     [e][d]
  bf16* Qw = Wpb + nWp;              // q (pre-scaled)     [h][s][d]
  bf16* Kw = Qw + HS;                // k                  [h][s][d]
  bf16* Vt = Kw + HS;                // v transposed       [h][d][s]
  bf16* At = Vt + HS;                // attention output   [s][h*64+d]
  // partials alias the dead region: 1536*4096 bf16 (12.58MB) + 98304 f32
  bf16* Opart = (bf16*)d_ws;
  float* Lpart = (float*)((short*)d_ws + (size_t)1536 * 4096);

  const int totalC = kNX8 + kNWq8 + kNWp8;
  k_cvt3<<<(totalC + 255) / 256, 256, 0, stream>>>(x, w_qkv, w_proj, Xb, Wqb, Wpb);

  k_qkv<<<dim3(kS / 128, kNE / 128), 256, 0, stream>>>(Xb, Wqb, Qw, Kw, Vw);
  k_vt<<<dim3(kS / 64, kNH), 256, 0, stream>>>(Vw, Vt);
  k_attn<<<dim3(2 * (kS / 64) * kNH), 256, 0, stream>>>(Qw, Kw, Vt, Opart, Lpart);
  k_comb<<<dim3((kS / 64) * kNH), 256, 0, stream>>>(Opart, Lpart, At);
  k_proj<<<dim3(kS / 64, kD / 64), 256, 0, stream>>>(At, Wpb, b_proj, out);
}

// Round 15
// 132.407 us; speedup vs baseline: 1.1923x; 1.0044x over previous
//
#include <hip/hip_runtime.h>
#include <hip/hip_bf16.h>
#include <math.h>

typedef short s16x8 __attribute__((ext_vector_type(8)));
typedef unsigned u32x2 __attribute__((ext_vector_type(2)));
typedef unsigned u32x4 __attribute__((ext_vector_type(4)));
typedef float f32x4 __attribute__((ext_vector_type(4)));
typedef float f32x16 __attribute__((ext_vector_type(16)));
typedef __hip_bfloat16 bf16;

#define GLD16(g, l)                                                        \
  __builtin_amdgcn_global_load_lds(                                        \
      (const __attribute__((address_space(1))) void*)(g),                  \
      (__attribute__((address_space(3))) void*)(l), 16, 0, 0)

#define MFMA16(a, b, c) __builtin_amdgcn_mfma_f32_16x16x32_bf16((a), (b), (c), 0, 0, 0)
#define MFMA32(a, b, c) __builtin_amdgcn_mfma_f32_32x32x16_bf16((a), (b), (c), 0, 0, 0)

static constexpr int kS = 4096;   // sequence length (64*64)
static constexpr int kD = 768;    // model dim
static constexpr int kNH = 12;    // heads
static constexpr int kHD = 64;    // head dim
static constexpr int kNE = 2304;  // 3*D
static constexpr int kNS = 3;     // kv-split factor (3-way: fits proven ws)

static __device__ __forceinline__ float bf2f(short s) {
  union { unsigned u; float f; } x;
  x.u = ((unsigned)(unsigned short)s) << 16;
  return x.f;
}

static __device__ __forceinline__ unsigned pk_bf16(float lo, float hi) {
  float2 f2;
  f2.x = lo;
  f2.y = hi;
  __hip_bfloat162 h2 = __float22bfloat162_rn(f2);
  return (unsigned)__bfloat16_as_ushort(h2.x) |
         ((unsigned)__bfloat16_as_ushort(h2.y) << 16);
}

// ===================== Kernel 0: fp32 -> bf16 conversion (all 3 tensors) ===
static constexpr int kNX8 = kS * kD / 8;      // 393216
static constexpr int kNWq8 = kNE * kD / 8;    // 221184
static constexpr int kNWp8 = kD * kD / 8;     // 73728

__global__ __launch_bounds__(256)
void k_cvt3(const float* __restrict__ x, const float* __restrict__ wq,
            const float* __restrict__ wp, bf16* __restrict__ xb,
            bf16* __restrict__ wqb, bf16* __restrict__ wpb) {
  int i = blockIdx.x * 256 + threadIdx.x;
  const float* src;
  short* dst;
  if (i < kNX8) {
    src = x; dst = (short*)xb;
  } else if (i < kNX8 + kNWq8) {
    i -= kNX8; src = wq; dst = (short*)wqb;
  } else {
    i -= kNX8 + kNWq8; if (i >= kNWp8) return;
    src = wp; dst = (short*)wpb;
  }
  const f32x4 a = *(const f32x4*)(src + i * 8);
  const f32x4 b = *(const f32x4*)(src + i * 8 + 4);
  s16x8 o;
#pragma unroll
  for (int j = 0; j < 4; ++j) {
    o[j] = (short)__bfloat16_as_ushort(__float2bfloat16(a[j]));
    o[j + 4] = (short)__bfloat16_as_ushort(__float2bfloat16(b[j]));
  }
  *(s16x8*)(dst + i * 8) = o;
}

// ===================== Kernel 1: QKV GEMM (2-phase dbuf) ===================
__global__ __launch_bounds__(256, 2)
void k_qkv(const bf16* __restrict__ X, const bf16* __restrict__ W,
           bf16* __restrict__ Qw, bf16* __restrict__ Kw, bf16* __restrict__ Vw) {
  __shared__ __align__(16) short As[2][128 * 32];
  __shared__ __align__(16) short Bs[2][128 * 32];
  const int tid = threadIdx.x;
  const int wv = tid >> 6, ln = tid & 63;
  const int r = ln & 15, kq = ln >> 4;
  const int bm = blockIdx.x * 128;   // s
  const int bn = blockIdx.y * 128;   // e
  const int wr = wv >> 1, wc = wv & 1;
  const short* Xs = (const short*)X;
  const short* Ws = (const short*)W;

  f32x4 acc[4][4] = {};

  const int c0 = wv * 128 + ln, c1 = c0 + 64;
  const int ra0 = c0 >> 2, ka0 = c0 & 3;
  const int ra1 = c1 >> 2, ka1 = c1 & 3;
  const int off0 = wv * 1024, off1 = off0 + 512;
  const short* gA0 = Xs + (bm + ra0) * kD + ka0 * 8;
  const short* gA1 = Xs + (bm + ra1) * kD + ka1 * 8;
  const short* gB0 = Ws + (bn + ra0) * kD + ka0 * 8;
  const short* gB1 = Ws + (bn + ra1) * kD + ka1 * 8;

  GLD16(gA0, &As[0][off0]);
  GLD16(gA1, &As[0][off1]);
  GLD16(gB0, &Bs[0][off0]);
  GLD16(gB1, &Bs[0][off1]);
  __syncthreads();

  const int NT = kD / 32;  // 24
  for (int t = 0; t < NT; ++t) {
    const short* aCur = As[t & 1];
    const short* bCur = Bs[t & 1];
    if (t + 1 < NT) {
      const int k1 = (t + 1) * 32;
      short* aN = As[(t + 1) & 1];
      short* bN = Bs[(t + 1) & 1];
      GLD16(gA0 + k1, aN + off0);
      GLD16(gA1 + k1, aN + off1);
      GLD16(gB0 + k1, bN + off0);
      GLD16(gB1 + k1, bN + off1);
    }
    s16x8 a[4], b[4];
#pragma unroll
    for (int i = 0; i < 4; ++i)
      a[i] = *(const s16x8*)(aCur + (wr * 64 + i * 16 + r) * 32 + kq * 8);
#pragma unroll
    for (int j = 0; j < 4; ++j)
      b[j] = *(const s16x8*)(bCur + (wc * 64 + j * 16 + r) * 32 + kq * 8);
#pragma unroll
    for (int i = 0; i < 4; ++i)
#pragma unroll
      for (int j = 0; j < 4; ++j) acc[i][j] = MFMA16(a[i], b[j], acc[i][j]);
    __syncthreads();
  }

  const int which = bn / kD;
  bf16* dst = (which == 0) ? Qw : (which == 1) ? Kw : Vw;
  const float scl = (which == 0) ? 0.125f : 1.0f;  // hd^-0.5, exact pow2
  const int ebase = bn - which * kD + wc * 64;
#pragma unroll
  for (int j = 0; j < 4; ++j) {
    const int e = ebase + j * 16 + r;
    const int h = e >> 6, d = e & 63;
#pragma unroll
    for (int i = 0; i < 4; ++i) {
      const int srow = bm + wr * 64 + i * 16 + kq * 4;
#pragma unroll
      for (int rr = 0; rr < 4; ++rr)
        dst[(h * kS + srow + rr) * kHD + d] = __float2bfloat16(acc[i][j][rr] * scl);
    }
  }
}

// ===================== Kernel 2: V transpose ===============================
__global__ __launch_bounds__(256, 2)
void k_vt(const bf16* __restrict__ Vw, bf16* __restrict__ Vt) {
  __shared__ __align__(16) short L[64 * 72];
  const int h = blockIdx.y, st = blockIdx.x;
  const int t = threadIdx.x;
  const short* src = (const short*)Vw + (h * kS + st * 64) * kHD;
  short* dstb = (short*)Vt + h * kHD * kS;
#pragma unroll
  for (int u = 0; u < 2; ++u) {
    const int c = u * 256 + t;
    const int row = c >> 3, ch = c & 7;
    *(s16x8*)(L + row * 72 + ch * 8) = *(const s16x8*)(src + row * kHD + ch * 8);
  }
  __syncthreads();
#pragma unroll
  for (int u = 0; u < 2; ++u) {
    const int c = u * 256 + t;
    const int d = c >> 3, ch = c & 7;
    s16x8 v;
#pragma unroll
    for (int j = 0; j < 8; ++j) v[j] = L[(ch * 8 + j) * 72 + d];
    *(s16x8*)(dstb + d * kS + st * 64 + ch * 8) = v;
  }
}

// ===================== Kernel 3: flash attention, 3-way kv-split ===========
// Grid 2304: block = (head, 64-q-tile, kv-THIRD: tiles [t0,t1) of 64).
// Math = round-12/14 proven body. More TLP (9 blocks/CU of work) -- the one
// lever with a confirmed gain (r12: 2-way split +13%; occupancy was 33%,
// no pipe saturated). Partials: bf16 unnormalized O + fp32 row-sums;
// k_comb normalizes IN-PLACE into slot j=0 (no At tensor -> fits proven ws).
__global__ __launch_bounds__(256, 5)
void k_attn(const bf16* __restrict__ Qw, const bf16* __restrict__ Kw,
            const bf16* __restrict__ Vt, bf16* __restrict__ Opart,
            float* __restrict__ Lpart) {
  __shared__ __align__(16) short Ks[2][64 * 64];  // [kv][d], swizzled chunks
  __shared__ __align__(16) short Vs[2][64 * 64];  // [d][kv], swizzled chunks
  const int tid = threadIdx.x;
  const int wv = tid >> 6, ln = tid & 63;
  const int qh = wv >> 1;    // q-subtile (32 rows)
  const int kvh = wv & 1;    // kv-half of each 64-tile
  const int col = ln & 31;
  const int lh = ln >> 5;

  // XCD-pair grouping (bijective): wg -> (pair p, b in [0,576));
  // b -> (hh 3/pair, qb in [0,64), j in [0,3)). 576 = 3*64*3.
  const int wg = blockIdx.x;
  const int p = (wg & 7) >> 1;
  const int b = ((wg >> 3) << 1) | (wg & 1);      // 0..575
  const int hh = 3 * p + b / 192;
  const int rem = b % 192;
  const int qb = rem / 3;
  const int j = rem % 3;
  const int q0 = qb * 64;
  const int pidx = (hh * 64 + qb) * kNS + j;
  const int t0 = (j * 64) / 3;        // 0, 21, 42
  const int t1 = ((j + 1) * 64) / 3;  // 21, 42, 64

  const short* Qh = (const short*)Qw + ((size_t)hh * kS + q0 + qh * 32) * kHD;
  const short* Kh = (const short*)Kw + (size_t)hh * kS * kHD;
  const short* Vh = (const short*)Vt + (size_t)hh * kHD * kS;

  // Q as B-operand frags: col = q (ln&31), k = kb*16 + lh*8 + {0..7}
  s16x8 bq[4];
#pragma unroll
  for (int kb = 0; kb < 4; ++kb)
    bq[kb] = *(const s16x8*)(Qh + col * kHD + kb * 16 + lh * 8);

  f32x16 o[2] = {};  // partial O[32q][64d] over this wave's kv share
  float lp = 0.f;

  // staging: 256 threads x 2 chunks per tensor; source-side XOR swizzle
  int ldso[2];
  const short* gK[2];
  const short* gV[2];
#pragma unroll
  for (int u = 0; u < 2; ++u) {
    const int c = u * 256 + tid;
    const int kr = c >> 3, g = (c & 7) ^ (kr & 7);
    ldso[u] = c * 8;
    gK[u] = Kh + kr * kHD + g * 8;
    gV[u] = Vh + kr * kS + g * 8;
  }

#pragma unroll
  for (int u = 0; u < 2; ++u) {
    GLD16(gK[u] + t0 * 64 * kHD, &Ks[0][ldso[u]]);
    GLD16(gV[u] + t0 * 64, &Vs[0][ldso[u]]);
  }
  __syncthreads();

  for (int kt = t0; kt < t1; ++kt) {
    const int i = kt - t0;
    const short* ksCur = Ks[i & 1];
    const short* vsCur = Vs[i & 1];
    if (kt + 1 < t1) {
      short* ksN = Ks[(i + 1) & 1];
      short* vsN = Vs[(i + 1) & 1];
      const int dk = (kt + 1) * 64 * kHD;
      const int dv = (kt + 1) * 64;
#pragma unroll
      for (int u = 0; u < 2; ++u) {
        GLD16(gK[u] + dk, ksN + ldso[u]);
        GLD16(gV[u] + dv, vsN + ldso[u]);
      }
    }

    // --- QK^T (swapped) for this wave's kv-half ---
    f32x16 z = {};
    const int krow = kvh * 32 + col;
    const int ksw = krow & 7;
    __builtin_amdgcn_s_setprio(1);
#pragma unroll
    for (int kb = 0; kb < 4; ++kb) {
      const int ch = ((kb << 1) + lh) ^ ksw;
      s16x8 ak = *(const s16x8*)(ksCur + krow * 64 + ch * 8);
      z = MFMA32(ak, bq[kb], z);
    }
    __builtin_amdgcn_s_setprio(0);

    // --- P = exp(S); packed RNE bf16 conversion ---
    float pv[16];
#pragma unroll
    for (int g = 0; g < 16; ++g) {
      pv[g] = __expf(z[g]);
      lp += pv[g];
    }
    unsigned own[8];
#pragma unroll
    for (int m = 0; m < 8; ++m)
      own[m] = pk_bf16(pv[2 * m], pv[2 * m + 1]);

    // --- PV: A-frags via permlane32_swap (round-11 verified) ---
    __builtin_amdgcn_s_setprio(1);
#pragma unroll
    for (int kvk = 0; kvk < 2; ++kvk) {
      u32x2 sA = __builtin_amdgcn_permlane32_swap(own[4 * kvk + 0], own[4 * kvk + 2], false, false);
      u32x2 sB = __builtin_amdgcn_permlane32_swap(own[4 * kvk + 1], own[4 * kvk + 3], false, false);
      u32x4 apv;
      apv[0] = sA[0];
      apv[1] = sB[0];
      apv[2] = sA[1];
      apv[3] = sB[1];
      const s16x8 ap = __builtin_bit_cast(s16x8, apv);
      const int kvg = kvh * 2 + kvk;
#pragma unroll
      for (int db = 0; db < 2; ++db) {
        const int vrow = db * 32 + col;
        const int ch = ((kvg << 1) + lh) ^ (vrow & 7);
        s16x8 vb = *(const s16x8*)(vsCur + vrow * 64 + ch * 8);
        o[db] = MFMA32(ap, vb, o[db]);
      }
    }
    __builtin_amdgcn_s_setprio(0);
    __syncthreads();
  }

  // --- combine kvh waves through (now-dead) LDS; write UNNORMALIZED partial
  lp += __shfl_xor(lp, 32);           // add other lh's kv rows within wave
  float* Of = (float*)Ks;             // [64 q][64 d] fp32 = 16 KB
  float* Lf = (float*)Vs;             // [64 q] row sums

  if (kvh == 1) {
#pragma unroll
    for (int db = 0; db < 2; ++db)
#pragma unroll
      for (int g = 0; g < 16; ++g) {
        const int qoff = (g & 3) + 8 * (g >> 2) + 4 * lh;
        Of[(qh * 32 + qoff) * 64 + db * 32 + col] = o[db][g];
      }
    if (lh == 0) Lf[qh * 32 + col] = lp;
  }
  __syncthreads();
  if (kvh == 0) {
    lp += Lf[qh * 32 + col];
    if (lh == 0) Lpart[pidx * 64 + qh * 32 + col] = lp;
    short* Ob = (short*)Opart + (size_t)pidx * 4096;
#pragma unroll
    for (int db = 0; db < 2; ++db)
#pragma unroll
      for (int g = 0; g < 16; ++g) {
        const int qoff = (g & 3) + 8 * (g >> 2) + 4 * lh;
        const float val = o[db][g] + Of[(qh * 32 + qoff) * 64 + db * 32 + col];
        Ob[(qh * 32 + qoff) * 64 + db * 32 + col] =
            (short)__bfloat16_as_ushort(__float2bfloat16(val));
      }
  }
}

// ===================== Kernel 3b: partial combine (IN-PLACE) ===============
// one block per (hh, qb): slot0 = (O0+O1+O2) / (l0+l1+l2). No At tensor;
// k_proj reads slot0 directly through a remapped address.
__global__ __launch_bounds__(256)
void k_comb(bf16* __restrict__ Opart, const float* __restrict__ Lpart) {
  const int blk = blockIdx.x;          // hh*64 + qb
  const int t = threadIdx.x;
  const int q = t >> 2;                // 0..63
  const int dg = t & 3;                // 16 d-elems each
  const int p0 = blk * kNS;
  const float inv = 1.0f / (Lpart[p0 * 64 + q] + Lpart[(p0 + 1) * 64 + q] +
                            Lpart[(p0 + 2) * 64 + q]);
  short* s0 = (short*)Opart + (size_t)p0 * 4096 + q * 64 + dg * 16;
  const short* s1 = s0 + 4096;
  const short* s2 = s0 + 8192;
#pragma unroll
  for (int jj = 0; jj < 2; ++jj) {
    const s16x8 a = *(const s16x8*)(s0 + jj * 8);
    const s16x8 bb = *(const s16x8*)(s1 + jj * 8);
    const s16x8 cc = *(const s16x8*)(s2 + jj * 8);
    s16x8 r;
#pragma unroll
    for (int e = 0; e < 8; ++e) {
      const float v = (bf2f(a[e]) + bf2f(bb[e]) + bf2f(cc[e])) * inv;
      r[e] = (short)__bfloat16_as_ushort(__float2bfloat16(v));
    }
    *(s16x8*)(s0 + jj * 8) = r;
  }
}

// ===================== Kernel 4: output projection ========================
// A is read from Opart slot-0: A[s][e] at ((e>>6)*64 + (s>>6))*3*4096 +
// (s&63)*64 + (e&63). With e = t*32 + ka*8 (ka<4): hh = t>>1,
// d = (t&1)*32 + ka*8 -- chunks never cross a 64-d boundary.
__global__ __launch_bounds__(256, 3)
void k_proj(const bf16* __restrict__ Opart, const bf16* __restrict__ W,
            const float* __restrict__ Bias, float* __restrict__ Out) {
  __shared__ __align__(16) short As[2][64 * 32];
  __shared__ __align__(16) short Bs[2][64 * 32];
  const int tid = threadIdx.x;
  const int wv = tid >> 6, ln = tid & 63;
  const int r = ln & 15, kq = ln >> 4;
  const int bm = blockIdx.x * 64;
  const int bn = blockIdx.y * 64;
  const int wr = wv >> 1, wc = wv & 1;
  const short* Asrc = (const short*)Opart;
  const short* Wsrc = (const short*)W;

  f32x4 acc[2][2] = {};
  const int c = wv * 64 + ln;
  const int ra = c >> 2, ka = c & 3;
  const int off = wv * 512;
  const int s = bm + ra;
  const int baseQ = (s >> 6) * (kNS * 4096) + (s & 63) * 64;  // qb*3*4096 + q*64
  const short* gB = Wsrc + (bn + ra) * kD + ka * 8;

  GLD16(Asrc + baseQ + ka * 8, &As[0][off]);  // t=0: hh=0, d=ka*8
  GLD16(gB, &Bs[0][off]);
  __syncthreads();

  const int NT = kD / 32;  // 24
  for (int t = 0; t < NT; ++t) {
    const short* aCur = As[t & 1];
    const short* bCur = Bs[t & 1];
    if (t + 1 < NT) {
      const int tn = t + 1;
      const int aoff = baseQ + (tn >> 1) * (64 * kNS * 4096) +
                       ((tn & 1) * 32 + ka * 8);
      GLD16(Asrc + aoff, &As[tn & 1][off]);
      GLD16(gB + tn * 32, &Bs[tn & 1][off]);
    }
    s16x8 a[2], b[2];
#pragma unroll
    for (int i = 0; i < 2; ++i)
      a[i] = *(const s16x8*)(aCur + (wr * 32 + i * 16 + r) * 32 + kq * 8);
#pragma unroll
    for (int jj = 0; jj < 2; ++jj)
      b[jj] = *(const s16x8*)(bCur + (wc * 32 + jj * 16 + r) * 32 + kq * 8);
#pragma unroll
    for (int i = 0; i < 2; ++i)
#pragma unroll
      for (int jj = 0; jj < 2; ++jj) acc[i][jj] = MFMA16(a[i], b[jj], acc[i][jj]);
    __syncthreads();
  }
#pragma unroll
  for (int jj = 0; jj < 2; ++jj) {
    const int e = bn + wc * 32 + jj * 16 + r;
    const float bv = Bias[e];
#pragma unroll
    for (int i = 0; i < 2; ++i) {
      const int srow = bm + wr * 32 + i * 16 + kq * 4;
#pragma unroll
      for (int rr = 0; rr < 4; ++rr)
        Out[(srow + rr) * kD + e] = acc[i][jj][rr] + bv;
    }
  }
}

// ===================== launcher ============================================
extern "C" void kernel_launch(void* const* d_in, const int* in_sizes, int n_in,
                              void* d_out, int out_size, void* d_ws, size_t ws_size,
                              hipStream_t stream) {
  const float* x = (const float*)d_in[0];
  const float* w_qkv = (const float*)d_in[1];
  const float* w_proj = (const float*)d_in[2];
  const float* b_proj = (const float*)d_in[3];
  float* out = (float*)d_out;

  const size_t HS = (size_t)kNH * kS * kHD;  // 3,145,728 elems per tensor
  const int nX = kS * kD;
  const int nWq = kNE * kD;
  const int nWp = kD * kD;

  // Layout: LIVE-through-attn tensors first, dead staging last; the 3-way
  // partial buffers alias the dead region (+2.75MB into proven-available
  // space: prior rounds actively used 42.5MB; this layout tops out at 39.5MB).
  bf16* Wpb = (bf16*)d_ws;           // w_proj bf16  [e][d]   1.18MB  live
  bf16* Qw = Wpb + nWp;              // q (scaled)   [h][s][d] 6.29MB live
  bf16* Kw = Qw + HS;                // k            [h][s][d] 6.29MB live
  bf16* Vt = Kw + HS;                // v transposed [h][d][s] 6.29MB live
  bf16* Xb = Vt + HS;                // x bf16       (dead after k_qkv)
  bf16* Wqb = Xb + nX;               // w_qkv bf16   (dead after k_qkv)
  bf16* Vw = Wqb + nWq;              // v            (dead after k_vt)
  // partials alias [Xb ...): 2304*4096 bf16 = 18.87MB + 2304*64 f32
  bf16* Opart = Xb;
  float* Lpart = (float*)((short*)Opart + (size_t)kNS * 768 * 4096);

  const int totalC = kNX8 + kNWq8 + kNWp8;
  k_cvt3<<<(totalC + 255) / 256, 256, 0, stream>>>(x, w_qkv, w_proj, Xb, Wqb, Wpb);

  k_qkv<<<dim3(kS / 128, kNE / 128), 256, 0, stream>>>(Xb, Wqb, Qw, Kw, Vw);
  k_vt<<<dim3(kS / 64, kNH), 256, 0, stream>>>(Vw, Vt);
  k_attn<<<dim3(kNS * (kS / 64) * kNH), 256, 0, stream>>>(Qw, Kw, Vt, Opart, Lpart);
  k_comb<<<dim3((kS / 64) * kNH), 256, 0, stream>>>(Opart, Lpart);
  k_proj<<<dim3(kS / 64, kD / 64), 256, 0, stream>>>(Opart, Wpb, b_proj, out);
}

// Round 16
// 126.849 us; speedup vs baseline: 1.2445x; 1.0438x over previous
//
#include <hip/hip_runtime.h>
#include <hip/hip_bf16.h>
#include <math.h>

typedef short s16x8 __attribute__((ext_vector_type(8)));
typedef unsigned u32x2 __attribute__((ext_vector_type(2)));
typedef unsigned u32x4 __attribute__((ext_vector_type(4)));
typedef float f32x4 __attribute__((ext_vector_type(4)));
typedef float f32x16 __attribute__((ext_vector_type(16)));
typedef __hip_bfloat16 bf16;

#define GLD16(g, l)                                                        \
  __builtin_amdgcn_global_load_lds(                                        \
      (const __attribute__((address_space(1))) void*)(g),                  \
      (__attribute__((address_space(3))) void*)(l), 16, 0, 0)

#define MFMA16(a, b, c) __builtin_amdgcn_mfma_f32_16x16x32_bf16((a), (b), (c), 0, 0, 0)
#define MFMA32(a, b, c) __builtin_amdgcn_mfma_f32_32x32x16_bf16((a), (b), (c), 0, 0, 0)

static constexpr int kS = 4096;   // sequence length (64*64)
static constexpr int kD = 768;    // model dim
static constexpr int kNH = 12;    // heads
static constexpr int kHD = 64;    // head dim
static constexpr int kNE = 2304;  // 3*D
static constexpr int kNS = 2;     // kv-split factor (2-way: r12-proven best)

static __device__ __forceinline__ float bf2f(short s) {
  union { unsigned u; float f; } x;
  x.u = ((unsigned)(unsigned short)s) << 16;
  return x.f;
}

// ===================== Kernel 0: fp32 -> bf16 conversion (all 3 tensors) ===
static constexpr int kNX8 = kS * kD / 8;      // 393216
static constexpr int kNWq8 = kNE * kD / 8;    // 221184
static constexpr int kNWp8 = kD * kD / 8;     // 73728

__global__ __launch_bounds__(256)
void k_cvt3(const float* __restrict__ x, const float* __restrict__ wq,
            const float* __restrict__ wp, bf16* __restrict__ xb,
            bf16* __restrict__ wqb, bf16* __restrict__ wpb) {
  int i = blockIdx.x * 256 + threadIdx.x;
  const float* src;
  short* dst;
  if (i < kNX8) {
    src = x; dst = (short*)xb;
  } else if (i < kNX8 + kNWq8) {
    i -= kNX8; src = wq; dst = (short*)wqb;
  } else {
    i -= kNX8 + kNWq8; if (i >= kNWp8) return;
    src = wp; dst = (short*)wpb;
  }
  const f32x4 a = *(const f32x4*)(src + i * 8);
  const f32x4 b = *(const f32x4*)(src + i * 8 + 4);
  s16x8 o;
#pragma unroll
  for (int j = 0; j < 4; ++j) {
    o[j] = (short)__bfloat16_as_ushort(__float2bfloat16(a[j]));
    o[j + 4] = (short)__bfloat16_as_ushort(__float2bfloat16(b[j]));
  }
  *(s16x8*)(dst + i * 8) = o;
}

// ===================== Kernel 1: QKV GEMM (2-phase dbuf) ===================
__global__ __launch_bounds__(256, 2)
void k_qkv(const bf16* __restrict__ X, const bf16* __restrict__ W,
           bf16* __restrict__ Qw, bf16* __restrict__ Kw, bf16* __restrict__ Vw) {
  __shared__ __align__(16) short As[2][128 * 32];
  __shared__ __align__(16) short Bs[2][128 * 32];
  const int tid = threadIdx.x;
  const int wv = tid >> 6, ln = tid & 63;
  const int r = ln & 15, kq = ln >> 4;
  const int bm = blockIdx.x * 128;   // s
  const int bn = blockIdx.y * 128;   // e
  const int wr = wv >> 1, wc = wv & 1;
  const short* Xs = (const short*)X;
  const short* Ws = (const short*)W;

  f32x4 acc[4][4] = {};

  const int c0 = wv * 128 + ln, c1 = c0 + 64;
  const int ra0 = c0 >> 2, ka0 = c0 & 3;
  const int ra1 = c1 >> 2, ka1 = c1 & 3;
  const int off0 = wv * 1024, off1 = off0 + 512;
  const short* gA0 = Xs + (bm + ra0) * kD + ka0 * 8;
  const short* gA1 = Xs + (bm + ra1) * kD + ka1 * 8;
  const short* gB0 = Ws + (bn + ra0) * kD + ka0 * 8;
  const short* gB1 = Ws + (bn + ra1) * kD + ka1 * 8;

  GLD16(gA0, &As[0][off0]);
  GLD16(gA1, &As[0][off1]);
  GLD16(gB0, &Bs[0][off0]);
  GLD16(gB1, &Bs[0][off1]);
  __syncthreads();

  const int NT = kD / 32;  // 24
  for (int t = 0; t < NT; ++t) {
    const short* aCur = As[t & 1];
    const short* bCur = Bs[t & 1];
    if (t + 1 < NT) {
      const int k1 = (t + 1) * 32;
      short* aN = As[(t + 1) & 1];
      short* bN = Bs[(t + 1) & 1];
      GLD16(gA0 + k1, aN + off0);
      GLD16(gA1 + k1, aN + off1);
      GLD16(gB0 + k1, bN + off0);
      GLD16(gB1 + k1, bN + off1);
    }
    s16x8 a[4], b[4];
#pragma unroll
    for (int i = 0; i < 4; ++i)
      a[i] = *(const s16x8*)(aCur + (wr * 64 + i * 16 + r) * 32 + kq * 8);
#pragma unroll
    for (int j = 0; j < 4; ++j)
      b[j] = *(const s16x8*)(bCur + (wc * 64 + j * 16 + r) * 32 + kq * 8);
#pragma unroll
    for (int i = 0; i < 4; ++i)
#pragma unroll
      for (int j = 0; j < 4; ++j) acc[i][j] = MFMA16(a[i], b[j], acc[i][j]);
    __syncthreads();
  }

  const int which = bn / kD;
  bf16* dst = (which == 0) ? Qw : (which == 1) ? Kw : Vw;
  const float scl = (which == 0) ? 0.125f : 1.0f;  // hd^-0.5, exact pow2
  const int ebase = bn - which * kD + wc * 64;
#pragma unroll
  for (int j = 0; j < 4; ++j) {
    const int e = ebase + j * 16 + r;
    const int h = e >> 6, d = e & 63;
#pragma unroll
    for (int i = 0; i < 4; ++i) {
      const int srow = bm + wr * 64 + i * 16 + kq * 4;
#pragma unroll
      for (int rr = 0; rr < 4; ++rr)
        dst[(h * kS + srow + rr) * kHD + d] = __float2bfloat16(acc[i][j][rr] * scl);
    }
  }
}

// ===================== Kernel 2: V transpose ===============================
__global__ __launch_bounds__(256, 2)
void k_vt(const bf16* __restrict__ Vw, bf16* __restrict__ Vt) {
  __shared__ __align__(16) short L[64 * 72];
  const int h = blockIdx.y, st = blockIdx.x;
  const int t = threadIdx.x;
  const short* src = (const short*)Vw + (h * kS + st * 64) * kHD;
  short* dstb = (short*)Vt + h * kHD * kS;
#pragma unroll
  for (int u = 0; u < 2; ++u) {
    const int c = u * 256 + t;
    const int row = c >> 3, ch = c & 7;
    *(s16x8*)(L + row * 72 + ch * 8) = *(const s16x8*)(src + row * kHD + ch * 8);
  }
  __syncthreads();
#pragma unroll
  for (int u = 0; u < 2; ++u) {
    const int c = u * 256 + t;
    const int d = c >> 3, ch = c & 7;
    s16x8 v;
#pragma unroll
    for (int j = 0; j < 8; ++j) v[j] = L[(ch * 8 + j) * 72 + d];
    *(s16x8*)(dstb + d * kS + st * 64 + ch * 8) = v;
  }
}

// ===================== Kernel 3: flash attention, 2-way kv-split ===========
// Structure = round-12 (proven best split) + round-15's in-place partials.
// ONE isolated change: P->bf16 via v_perm_b32 TRUNCATION (1 op/pair vs ~9
// for software RNE; r14 proved the compiler won't emit packed cvt). P>0
// always; truncation bias <=1 ULP (avg -0.195%), lp stays exact fp32 ->
// predicted absmax ~2e-4, threshold 5.9e-4.
__global__ __launch_bounds__(256, 5)
void k_attn(const bf16* __restrict__ Qw, const bf16* __restrict__ Kw,
            const bf16* __restrict__ Vt, bf16* __restrict__ Opart,
            float* __restrict__ Lpart) {
  __shared__ __align__(16) short Ks[2][64 * 64];  // [kv][d], swizzled chunks
  __shared__ __align__(16) short Vs[2][64 * 64];  // [d][kv], swizzled chunks
  const int tid = threadIdx.x;
  const int wv = tid >> 6, ln = tid & 63;
  const int qh = wv >> 1;    // q-subtile (32 rows)
  const int kvh = wv & 1;    // kv-half of each 64-tile
  const int col = ln & 31;
  const int lh = ln >> 5;

  // XCD-pair grouping (bijective, r12-proven): wg -> (pair p, b in [0,384))
  const int wg = blockIdx.x;
  const int p = (wg & 7) >> 1;
  const int b = ((wg >> 3) << 1) | (wg & 1);      // 0..383
  const int hh = 3 * p + (b >> 7);
  const int rem = b & 127;
  const int qb = rem >> 1;
  const int j = rem & 1;
  const int q0 = qb * 64;
  const int pidx = (hh * 64 + qb) * kNS + j;

  const short* Qh = (const short*)Qw + ((size_t)hh * kS + q0 + qh * 32) * kHD;
  const short* Kh = (const short*)Kw + (size_t)hh * kS * kHD + (size_t)j * 2048 * kHD;
  const short* Vh = (const short*)Vt + (size_t)hh * kHD * kS + j * 2048;

  // Q as B-operand frags: col = q (ln&31), k = kb*16 + lh*8 + {0..7}
  s16x8 bq[4];
#pragma unroll
  for (int kb = 0; kb < 4; ++kb)
    bq[kb] = *(const s16x8*)(Qh + col * kHD + kb * 16 + lh * 8);

  f32x16 o[2] = {};  // partial O[32q][64d] over this wave's kv share
  float lp = 0.f;

  // staging: 256 threads x 2 chunks per tensor; source-side XOR swizzle
  int ldso[2];
  const short* gK[2];
  const short* gV[2];
#pragma unroll
  for (int u = 0; u < 2; ++u) {
    const int c = u * 256 + tid;
    const int kr = c >> 3, g = (c & 7) ^ (kr & 7);
    ldso[u] = c * 8;
    gK[u] = Kh + kr * kHD + g * 8;
    gV[u] = Vh + kr * kS + g * 8;
  }

#pragma unroll
  for (int u = 0; u < 2; ++u) {
    GLD16(gK[u], &Ks[0][ldso[u]]);
    GLD16(gV[u], &Vs[0][ldso[u]]);
  }
  __syncthreads();

  const int NT2 = 32;  // this block's 32 kv tiles (2048 rows)
  for (int kt = 0; kt < NT2; ++kt) {
    const short* ksCur = Ks[kt & 1];
    const short* vsCur = Vs[kt & 1];
    if (kt + 1 < NT2) {
      short* ksN = Ks[(kt + 1) & 1];
      short* vsN = Vs[(kt + 1) & 1];
      const int dk = (kt + 1) * 64 * kHD;
      const int dv = (kt + 1) * 64;
#pragma unroll
      for (int u = 0; u < 2; ++u) {
        GLD16(gK[u] + dk, ksN + ldso[u]);
        GLD16(gV[u] + dv, vsN + ldso[u]);
      }
    }

    // --- QK^T (swapped) for this wave's kv-half ---
    f32x16 z = {};
    const int krow = kvh * 32 + col;
    const int ksw = krow & 7;
    __builtin_amdgcn_s_setprio(1);
#pragma unroll
    for (int kb = 0; kb < 4; ++kb) {
      const int ch = ((kb << 1) + lh) ^ ksw;
      s16x8 ak = *(const s16x8*)(ksCur + krow * 64 + ch * 8);
      z = MFMA32(ak, bq[kb], z);
    }
    __builtin_amdgcn_s_setprio(0);

    // --- P = exp(S); TRUNCATION pack via v_perm_b32 (1 op per pair) ---
    float pv[16];
#pragma unroll
    for (int g = 0; g < 16; ++g) {
      pv[g] = __expf(z[g]);
      lp += pv[g];
    }
    unsigned own[8];
#pragma unroll
    for (int m = 0; m < 8; ++m) {
      const unsigned f0 = __builtin_bit_cast(unsigned, pv[2 * m]);
      const unsigned f1 = __builtin_bit_cast(unsigned, pv[2 * m + 1]);
      // result bytes [0,1]=f0 bytes[2,3] (lo16=pv0 hi), [2,3]=f1 bytes[2,3]
      own[m] = __builtin_amdgcn_perm(f1, f0, 0x07060302u);
    }

    // --- PV: A-frags via permlane32_swap (round-11 verified) ---
    __builtin_amdgcn_s_setprio(1);
#pragma unroll
    for (int kvk = 0; kvk < 2; ++kvk) {
      u32x2 sA = __builtin_amdgcn_permlane32_swap(own[4 * kvk + 0], own[4 * kvk + 2], false, false);
      u32x2 sB = __builtin_amdgcn_permlane32_swap(own[4 * kvk + 1], own[4 * kvk + 3], false, false);
      u32x4 apv;
      apv[0] = sA[0];
      apv[1] = sB[0];
      apv[2] = sA[1];
      apv[3] = sB[1];
      const s16x8 ap = __builtin_bit_cast(s16x8, apv);
      const int kvg = kvh * 2 + kvk;
#pragma unroll
      for (int db = 0; db < 2; ++db) {
        const int vrow = db * 32 + col;
        const int ch = ((kvg << 1) + lh) ^ (vrow & 7);
        s16x8 vb = *(const s16x8*)(vsCur + vrow * 64 + ch * 8);
        o[db] = MFMA32(ap, vb, o[db]);
      }
    }
    __builtin_amdgcn_s_setprio(0);
    __syncthreads();
  }

  // --- combine kvh waves through (now-dead) LDS; write UNNORMALIZED partial
  lp += __shfl_xor(lp, 32);           // add other lh's kv rows within wave
  float* Of = (float*)Ks;             // [64 q][64 d] fp32 = 16 KB
  float* Lf = (float*)Vs;             // [64 q] row sums

  if (kvh == 1) {
#pragma unroll
    for (int db = 0; db < 2; ++db)
#pragma unroll
      for (int g = 0; g < 16; ++g) {
        const int qoff = (g & 3) + 8 * (g >> 2) + 4 * lh;
        Of[(qh * 32 + qoff) * 64 + db * 32 + col] = o[db][g];
      }
    if (lh == 0) Lf[qh * 32 + col] = lp;
  }
  __syncthreads();
  if (kvh == 0) {
    lp += Lf[qh * 32 + col];
    if (lh == 0) Lpart[pidx * 64 + qh * 32 + col] = lp;
    short* Ob = (short*)Opart + (size_t)pidx * 4096;
#pragma unroll
    for (int db = 0; db < 2; ++db)
#pragma unroll
      for (int g = 0; g < 16; ++g) {
        const int qoff = (g & 3) + 8 * (g >> 2) + 4 * lh;
        const float val = o[db][g] + Of[(qh * 32 + qoff) * 64 + db * 32 + col];
        Ob[(qh * 32 + qoff) * 64 + db * 32 + col] =
            (short)__bfloat16_as_ushort(__float2bfloat16(val));
      }
  }
}

// ===================== Kernel 3b: partial combine (IN-PLACE) ===============
// one block per (hh, qb): slot0 = (O0+O1) / (l0+l1). No At tensor.
__global__ __launch_bounds__(256)
void k_comb(bf16* __restrict__ Opart, const float* __restrict__ Lpart) {
  const int blk = blockIdx.x;          // hh*64 + qb
  const int t = threadIdx.x;
  const int q = t >> 2;                // 0..63
  const int dg = t & 3;                // 16 d-elems each
  const int p0 = blk * kNS;
  const float inv = 1.0f / (Lpart[p0 * 64 + q] + Lpart[(p0 + 1) * 64 + q]);
  short* s0 = (short*)Opart + (size_t)p0 * 4096 + q * 64 + dg * 16;
  const short* s1 = s0 + 4096;
#pragma unroll
  for (int jj = 0; jj < 2; ++jj) {
    const s16x8 a = *(const s16x8*)(s0 + jj * 8);
    const s16x8 bb = *(const s16x8*)(s1 + jj * 8);
    s16x8 r;
#pragma unroll
    for (int e = 0; e < 8; ++e) {
      const float v = (bf2f(a[e]) + bf2f(bb[e])) * inv;
      r[e] = (short)__bfloat16_as_ushort(__float2bfloat16(v));
    }
    *(s16x8*)(s0 + jj * 8) = r;
  }
}

// ===================== Kernel 4: output projection ========================
// A read from Opart slot-0 (r15-proven remap): A[s][e] at
// ((e>>6)*64 + (s>>6))*kNS*4096 + (s&63)*64 + (e&63).
__global__ __launch_bounds__(256, 3)
void k_proj(const bf16* __restrict__ Opart, const bf16* __restrict__ W,
            const float* __restrict__ Bias, float* __restrict__ Out) {
  __shared__ __align__(16) short As[2][64 * 32];
  __shared__ __align__(16) short Bs[2][64 * 32];
  const int tid = threadIdx.x;
  const int wv = tid >> 6, ln = tid & 63;
  const int r = ln & 15, kq = ln >> 4;
  const int bm = blockIdx.x * 64;
  const int bn = blockIdx.y * 64;
  const int wr = wv >> 1, wc = wv & 1;
  const short* Asrc = (const short*)Opart;
  const short* Wsrc = (const short*)W;

  f32x4 acc[2][2] = {};
  const int c = wv * 64 + ln;
  const int ra = c >> 2, ka = c & 3;
  const int off = wv * 512;
  const int s = bm + ra;
  const int baseQ = (s >> 6) * (kNS * 4096) + (s & 63) * 64;
  const short* gB = Wsrc + (bn + ra) * kD + ka * 8;

  GLD16(Asrc + baseQ + ka * 8, &As[0][off]);  // t=0: hh=0, d=ka*8
  GLD16(gB, &Bs[0][off]);
  __syncthreads();

  const int NT = kD / 32;  // 24
  for (int t = 0; t < NT; ++t) {
    const short* aCur = As[t & 1];
    const short* bCur = Bs[t & 1];
    if (t + 1 < NT) {
      const int tn = t + 1;
      const int aoff = baseQ + (tn >> 1) * (64 * kNS * 4096) +
                       ((tn & 1) * 32 + ka * 8);
      GLD16(Asrc + aoff, &As[tn & 1][off]);
      GLD16(gB + tn * 32, &Bs[tn & 1][off]);
    }
    s16x8 a[2], b[2];
#pragma unroll
    for (int i = 0; i < 2; ++i)
      a[i] = *(const s16x8*)(aCur + (wr * 32 + i * 16 + r) * 32 + kq * 8);
#pragma unroll
    for (int jj = 0; jj < 2; ++jj)
      b[jj] = *(const s16x8*)(bCur + (wc * 32 + jj * 16 + r) * 32 + kq * 8);
#pragma unroll
    for (int i = 0; i < 2; ++i)
#pragma unroll
      for (int jj = 0; jj < 2; ++jj) acc[i][jj] = MFMA16(a[i], b[jj], acc[i][jj]);
    __syncthreads();
  }
#pragma unroll
  for (int jj = 0; jj < 2; ++jj) {
    const int e = bn + wc * 32 + jj * 16 + r;
    const float bv = Bias[e];
#pragma unroll
    for (int i = 0; i < 2; ++i) {
      const int srow = bm + wr * 32 + i * 16 + kq * 4;
#pragma unroll
      for (int rr = 0; rr < 4; ++rr)
        Out[(srow + rr) * kD + e] = acc[i][jj][rr] + bv;
    }
  }
}

// ===================== launcher ============================================
extern "C" void kernel_launch(void* const* d_in, const int* in_sizes, int n_in,
                              void* d_out, int out_size, void* d_ws, size_t ws_size,
                              hipStream_t stream) {
  const float* x = (const float*)d_in[0];
  const float* w_qkv = (const float*)d_in[1];
  const float* w_proj = (const float*)d_in[2];
  const float* b_proj = (const float*)d_in[3];
  float* out = (float*)d_out;

  const size_t HS = (size_t)kNH * kS * kHD;  // 3,145,728 elems per tensor
  const int nX = kS * kD;
  const int nWq = kNE * kD;
  const int nWp = kD * kD;

  // Layout: LIVE-through-attn tensors first, dead staging last; 2-way
  // partial buffers alias the dead region (12.6MB < 16.1MB available).
  bf16* Wpb = (bf16*)d_ws;           // w_proj bf16  [e][d]   live
  bf16* Qw = Wpb + nWp;              // q (scaled)   [h][s][d] live
  bf16* Kw = Qw + HS;                // k            [h][s][d] live
  bf16* Vt = Kw + HS;                // v transposed [h][d][s] live
  bf16* Xb = Vt + HS;                // x bf16       (dead after k_qkv)
  bf16* Wqb = Xb + nX;               // w_qkv bf16   (dead after k_qkv)
  bf16* Vw = Wqb + nWq;              // v            (dead after k_vt)
  bf16* Opart = Xb;                  // kNS*768*4096 bf16 = 12.58MB
  float* Lpart = (float*)((short*)Opart + (size_t)kNS * 768 * 4096);

  const int totalC = kNX8 + kNWq8 + kNWp8;
  k_cvt3<<<(totalC + 255) / 256, 256, 0, stream>>>(x, w_qkv, w_proj, Xb, Wqb, Wpb);

  k_qkv<<<dim3(kS / 128, kNE / 128), 256, 0, stream>>>(Xb, Wqb, Qw, Kw, Vw);
  k_vt<<<dim3(kS / 64, kNH), 256, 0, stream>>>(Vw, Vt);
  k_attn<<<dim3(kNS * (kS / 64) * kNH), 256, 0, stream>>>(Qw, Kw, Vt, Opart, Lpart);
  k_comb<<<dim3((kS / 64) * kNH), 256, 0, stream>>>(Opart, Lpart);
  k_proj<<<dim3(kS / 64, kD / 64), 256, 0, stream>>>(Opart, Wpb, b_proj, out);
}